// Round 1
// baseline (1697.069 us; speedup 1.0000x reference)
//
#include <hip/hip_runtime.h>
#include <hip/hip_bf16.h>
#include <math.h>

#define HC 256
#define NH 8
#define NC 32
#define NEG_SLOPE 0.2f

// ---------------------------------------------------------------------------
// GEMM: C[M,Nn] = A[M,K] @ B[K,Nn], all row-major fp32. Nn is a multiple of 128,
// K a multiple of 8. 128x128 tile, BK=8, 256 threads, 8x8 micro-tile.
// ---------------------------------------------------------------------------
__global__ __launch_bounds__(256) void gemm_f32(const float* __restrict__ A,
                                                const float* __restrict__ B,
                                                float* __restrict__ Cmat,
                                                int M, int K, int Nn) {
    __shared__ float As[8][128];
    __shared__ float Bs[8][128];
    const int tid = threadIdx.x;
    const int rowBase = blockIdx.x * 128;
    const int colBase = blockIdx.y * 128;
    const int tr = tid >> 4;   // 0..15
    const int tc = tid & 15;   // 0..15

    float acc[8][8];
#pragma unroll
    for (int i = 0; i < 8; i++)
#pragma unroll
        for (int j = 0; j < 8; j++) acc[i][j] = 0.f;

    // A staging map: each thread loads float4 at (row am, k ak..ak+3)
    const int am = tid >> 1;
    const int ak = (tid & 1) * 4;
    // B staging map: each thread loads float4 at (k bk, col bn..bn+3)
    const int bk = tid >> 5;          // 0..7
    const int bn = (tid & 31) * 4;    // 0..124

    for (int k0 = 0; k0 < K; k0 += 8) {
        float4 av = make_float4(0.f, 0.f, 0.f, 0.f);
        const int ar = rowBase + am;
        if (ar < M) av = *reinterpret_cast<const float4*>(&A[(size_t)ar * K + k0 + ak]);
        As[ak + 0][am] = av.x;
        As[ak + 1][am] = av.y;
        As[ak + 2][am] = av.z;
        As[ak + 3][am] = av.w;

        const float4 bv =
            *reinterpret_cast<const float4*>(&B[(size_t)(k0 + bk) * Nn + colBase + bn]);
        *reinterpret_cast<float4*>(&Bs[bk][bn]) = bv;
        __syncthreads();

#pragma unroll
        for (int kk = 0; kk < 8; kk++) {
            float a[8], b[8];
#pragma unroll
            for (int i = 0; i < 8; i++) a[i] = As[kk][tr * 8 + i];
#pragma unroll
            for (int j = 0; j < 8; j++) b[j] = Bs[kk][tc * 8 + j];
#pragma unroll
            for (int i = 0; i < 8; i++)
#pragma unroll
                for (int j = 0; j < 8; j++) acc[i][j] += a[i] * b[j];
        }
        __syncthreads();
    }

#pragma unroll
    for (int i = 0; i < 8; i++) {
        const int r = rowBase + tr * 8 + i;
        if (r < M) {
            float4 v0 = make_float4(acc[i][0], acc[i][1], acc[i][2], acc[i][3]);
            float4 v1 = make_float4(acc[i][4], acc[i][5], acc[i][6], acc[i][7]);
            *reinterpret_cast<float4*>(&Cmat[(size_t)r * Nn + colBase + tc * 8]) = v0;
            *reinterpret_cast<float4*>(&Cmat[(size_t)r * Nn + colBase + tc * 8 + 4]) = v1;
        }
    }
}

// ---------------------------------------------------------------------------
// Per-node attention coefficients: a_src[n,h] = sum_c h[n,h,c]*att_src[h,c]
// block = 256 threads (one node), 32-lane group per head.
// ---------------------------------------------------------------------------
__global__ __launch_bounds__(256) void attn_coef(const float* __restrict__ h,
                                                 const float* __restrict__ att_s,
                                                 const float* __restrict__ att_d,
                                                 float* __restrict__ a_src,
                                                 float* __restrict__ a_dst) {
    const int n = blockIdx.x;
    const int tid = threadIdx.x;
    const float hv = h[(size_t)n * HC + tid];
    float p = hv * att_s[tid];
    float q = hv * att_d[tid];
#pragma unroll
    for (int m = 16; m >= 1; m >>= 1) {
        p += __shfl_xor(p, m);
        q += __shfl_xor(q, m);
    }
    if ((tid & 31) == 0) {
        a_src[n * NH + (tid >> 5)] = p;
        a_dst[n * NH + (tid >> 5)] = q;
    }
}

// ---------------------------------------------------------------------------
// CSR build
// ---------------------------------------------------------------------------
__global__ void count_deg(const int* __restrict__ dst, int E, int ET, int* __restrict__ deg) {
    const int e = blockIdx.x * blockDim.x + threadIdx.x;
    if (e >= ET) return;
    const int d = (e < E) ? dst[e] : (e - E);
    atomicAdd(&deg[d], 1);
}

// single-block exclusive scan: row_ptr[0]=0, row_ptr[i+1]=sum(deg[0..i])
__global__ __launch_bounds__(1024) void scan_deg(const int* __restrict__ deg,
                                                 int* __restrict__ row_ptr, int N) {
    __shared__ int sdata[1024];
    __shared__ int carry;
    const int tid = threadIdx.x;
    if (tid == 0) {
        carry = 0;
        row_ptr[0] = 0;
    }
    __syncthreads();
    for (int base = 0; base < N; base += 1024) {
        const int i = base + tid;
        int v = (i < N) ? deg[i] : 0;
        sdata[tid] = v;
        __syncthreads();
        for (int off = 1; off < 1024; off <<= 1) {
            int t = 0;
            if (tid >= off) t = sdata[tid - off];
            __syncthreads();
            sdata[tid] += t;
            __syncthreads();
        }
        const int inc = sdata[tid] + carry;
        if (i < N) row_ptr[i + 1] = inc;
        __syncthreads();
        if (tid == 1023) carry = inc;
        __syncthreads();
    }
}

__global__ void scatter_edges(const int* __restrict__ dst, int E, int ET,
                              const int* __restrict__ row_ptr, int* __restrict__ cursor,
                              int* __restrict__ eids) {
    const int e = blockIdx.x * blockDim.x + threadIdx.x;
    if (e >= ET) return;
    const int d = (e < E) ? dst[e] : (e - E);
    const int pos = atomicAdd(&cursor[d], 1);
    eids[row_ptr[d] + pos] = e;
}

// ---------------------------------------------------------------------------
// GAT aggregation: one block (256 threads) per destination node.
// Phase 1: per-head segment max + exp-sum over incoming edges.
// Phase 2: out[n,f] = relu( bias[f] + sum_e alpha[e,h] * h[src_e, f] )
// ---------------------------------------------------------------------------
__global__ __launch_bounds__(256) void gat_aggregate(
    const float* __restrict__ h, const float* __restrict__ a_src,
    const float* __restrict__ a_dst, const int* __restrict__ row_ptr,
    const int* __restrict__ eids, const int* __restrict__ src_arr, int E,
    const float* __restrict__ bias, float* __restrict__ out) {
    const int n = blockIdx.x;
    const int tid = threadIdx.x;
    const int beg = row_ptr[n];
    const int deg = row_ptr[n + 1] - beg;

    __shared__ float red[256];
    __shared__ float mx[NH];
    __shared__ float dnm[NH];

    const int hh = tid & 7;     // head for phase 1
    const int slot = tid >> 3;  // 0..31 edge-slot
    const float ad1 = a_dst[n * NH + hh];

    // phase 1a: per-head max
    float lmax = -1e30f;
    for (int j = slot; j < deg; j += 32) {
        const int e = eids[beg + j];
        const int s = (e < E) ? src_arr[e] : (e - E);
        float v = a_src[s * NH + hh] + ad1;
        v = (v > 0.f) ? v : NEG_SLOPE * v;
        lmax = fmaxf(lmax, v);
    }
    red[tid] = lmax;
    __syncthreads();
    for (int off = 128; off >= 8; off >>= 1) {
        if (tid < off) red[tid] = fmaxf(red[tid], red[tid + off]);
        __syncthreads();
    }
    if (tid < NH) mx[tid] = red[tid];
    __syncthreads();

    // phase 1b: per-head sum of exp
    const float m_h = mx[hh];
    float lsum = 0.f;
    for (int j = slot; j < deg; j += 32) {
        const int e = eids[beg + j];
        const int s = (e < E) ? src_arr[e] : (e - E);
        float v = a_src[s * NH + hh] + ad1;
        v = (v > 0.f) ? v : NEG_SLOPE * v;
        lsum += __expf(v - m_h);
    }
    red[tid] = lsum;
    __syncthreads();
    for (int off = 128; off >= 8; off >>= 1) {
        if (tid < off) red[tid] += red[tid + off];
        __syncthreads();
    }
    if (tid < NH) dnm[tid] = red[tid];
    __syncthreads();

    // phase 2: weighted accumulate; thread tid owns feature f=tid, head tid>>5
    const int h8 = tid >> 5;
    const float m2 = mx[h8];
    const float invd = 1.f / (dnm[h8] + 1e-16f);
    const float ad2 = a_dst[n * NH + h8];
    float acc = 0.f;
    for (int j = 0; j < deg; j++) {
        const int e = eids[beg + j];
        const int s = (e < E) ? src_arr[e] : (e - E);
        float v = a_src[s * NH + h8] + ad2;
        v = (v > 0.f) ? v : NEG_SLOPE * v;
        const float al = __expf(v - m2) * invd;
        acc += al * h[(size_t)s * HC + tid];
    }
    out[(size_t)n * HC + tid] = fmaxf(acc + bias[tid], 0.f);  // + bias, ReLU
}

// ---------------------------------------------------------------------------
// Global mean pool: batch is sorted; one block (256 threads) per graph.
// ---------------------------------------------------------------------------
__global__ __launch_bounds__(256) void pool_mean(const float* __restrict__ h,
                                                 const int* __restrict__ batch, int N,
                                                 float* __restrict__ pooled) {
    const int g = blockIdx.x;
    const int tid = threadIdx.x;
    int lo = 0, hi = N;
    while (lo < hi) {
        const int mid = (lo + hi) >> 1;
        if (batch[mid] < g) lo = mid + 1; else hi = mid;
    }
    const int start = lo;
    hi = N;
    while (lo < hi) {
        const int mid = (lo + hi) >> 1;
        if (batch[mid] < g + 1) lo = mid + 1; else hi = mid;
    }
    const int end = lo;
    float acc = 0.f;
    for (int n = start; n < end; n++) acc += h[(size_t)n * HC + tid];
    const float cnt = (float)(end - start);
    pooled[g * HC + tid] = acc / fmaxf(cnt, 1.0f);
}

// ---------------------------------------------------------------------------
// MLP head: z = relu(pooled @ lin1_w + lin1_b); out = z @ lin2_w + lin2_b
// one block (128 threads) per graph.
// ---------------------------------------------------------------------------
__global__ __launch_bounds__(128) void mlp_head(const float* __restrict__ pooled,
                                                const float* __restrict__ w1,
                                                const float* __restrict__ b1,
                                                const float* __restrict__ w2,
                                                const float* __restrict__ b2,
                                                float* __restrict__ out) {
    const int g = blockIdx.x;
    const int tid = threadIdx.x;
    __shared__ float p[HC];
    p[tid] = pooled[g * HC + tid];
    p[tid + 128] = pooled[g * HC + tid + 128];
    __syncthreads();
    float z = b1[tid];
#pragma unroll 8
    for (int k = 0; k < HC; k++) z += p[k] * w1[k * 128 + tid];
    z = fmaxf(z, 0.f);
    float t = z * w2[tid];
#pragma unroll
    for (int m = 32; m >= 1; m >>= 1) t += __shfl_xor(t, m);
    __shared__ float ws2[2];
    if ((tid & 63) == 0) ws2[tid >> 6] = t;
    __syncthreads();
    if (tid == 0) out[g] = ws2[0] + ws2[1] + b2[0];
}

// ---------------------------------------------------------------------------
// Host-side launcher
// ---------------------------------------------------------------------------
extern "C" void kernel_launch(void* const* d_in, const int* in_sizes, int n_in,
                              void* d_out, int out_size, void* d_ws, size_t ws_size,
                              hipStream_t stream) {
    const float* x      = (const float*)d_in[0];
    const int*   ei     = (const int*)d_in[1];
    const int*   batch  = (const int*)d_in[2];
    const float* W1     = (const float*)d_in[3];
    const float* as1    = (const float*)d_in[4];
    const float* ad1    = (const float*)d_in[5];
    const float* b1     = (const float*)d_in[6];
    const float* W2     = (const float*)d_in[7];
    const float* as2    = (const float*)d_in[8];
    const float* ad2    = (const float*)d_in[9];
    const float* b2     = (const float*)d_in[10];
    const float* lin1w  = (const float*)d_in[11];
    const float* lin1b  = (const float*)d_in[12];
    const float* lin2w  = (const float*)d_in[13];
    const float* lin2b  = (const float*)d_in[14];

    const int N  = in_sizes[2];          // 50000
    const int E  = in_sizes[1] / 2;      // 800000
    const int ET = E + N;                // + self-loops
    const int Fin = in_sizes[0] / N;     // 1280
    const int NG = 64;

    const int* src_arr = ei;
    const int* dst_arr = ei + E;

    // workspace carve-up (aligned to 256B)
    char* ws = (char*)d_ws;
    size_t off = 0;
    auto alloc = [&](size_t bytes) {
        void* p = ws + off;
        off += (bytes + 255) & ~(size_t)255;
        return p;
    };
    float* h_gemm  = (float*)alloc((size_t)N * HC * sizeof(float));
    float* h_agg   = (float*)alloc((size_t)N * HC * sizeof(float));
    float* a_src   = (float*)alloc((size_t)N * NH * sizeof(float));
    float* a_dst   = (float*)alloc((size_t)N * NH * sizeof(float));
    int*   deg     = (int*)alloc((size_t)N * sizeof(int));
    int*   cursor  = (int*)alloc((size_t)N * sizeof(int));
    int*   row_ptr = (int*)alloc((size_t)(N + 1) * sizeof(int));
    int*   eids    = (int*)alloc((size_t)ET * sizeof(int));
    float* pooled  = (float*)alloc((size_t)NG * HC * sizeof(float));
    (void)ws_size; (void)n_in; (void)out_size;

    // ---- CSR build (shared by both layers) ----
    hipMemsetAsync(deg, 0, (size_t)N * sizeof(int), stream);
    hipMemsetAsync(cursor, 0, (size_t)N * sizeof(int), stream);
    {
        const int blocks = (ET + 255) / 256;
        count_deg<<<blocks, 256, 0, stream>>>(dst_arr, E, ET, deg);
        scan_deg<<<1, 1024, 0, stream>>>(deg, row_ptr, N);
        scatter_edges<<<blocks, 256, 0, stream>>>(dst_arr, E, ET, row_ptr, cursor, eids);
    }

    // ---- Layer 1 ----
    gemm_f32<<<dim3((N + 127) / 128, HC / 128), 256, 0, stream>>>(x, W1, h_gemm, N, Fin, HC);
    attn_coef<<<N, 256, 0, stream>>>(h_gemm, as1, ad1, a_src, a_dst);
    gat_aggregate<<<N, 256, 0, stream>>>(h_gemm, a_src, a_dst, row_ptr, eids, src_arr, E,
                                         b1, h_agg);

    // ---- Layer 2 ----
    gemm_f32<<<dim3((N + 127) / 128, HC / 128), 256, 0, stream>>>(h_agg, W2, h_gemm, N, HC, HC);
    attn_coef<<<N, 256, 0, stream>>>(h_gemm, as2, ad2, a_src, a_dst);
    gat_aggregate<<<N, 256, 0, stream>>>(h_gemm, a_src, a_dst, row_ptr, eids, src_arr, E,
                                         b2, h_agg);

    // ---- Pool + MLP head ----
    pool_mean<<<NG, 256, 0, stream>>>(h_agg, batch, N, pooled);
    mlp_head<<<NG, 128, 0, stream>>>(pooled, lin1w, lin1b, lin2w, lin2b, (float*)d_out);
}

// Round 2
// 1316.334 us; speedup vs baseline: 1.2892x; 1.2892x over previous
//
#include <hip/hip_runtime.h>
#include <hip/hip_bf16.h>
#include <math.h>

#define HC 256
#define NH 8
#define NEG_SLOPE 0.2f

typedef unsigned short u16;
typedef __attribute__((ext_vector_type(8))) short bf16x8;
typedef __attribute__((ext_vector_type(4))) float f32x4;

__device__ __forceinline__ u16 f2bf(float f) {
    unsigned int u = __float_as_uint(f);
    u += 0x7FFFu + ((u >> 16) & 1u);
    return (u16)(u >> 16);
}
__device__ __forceinline__ float bf2f(u16 s) {
    return __uint_as_float(((unsigned int)s) << 16);
}

__device__ __forceinline__ void glds16(const u16* g, u16* l) {
    __builtin_amdgcn_global_load_lds(
        (const __attribute__((address_space(1))) void*)g,
        (__attribute__((address_space(3))) void*)l, 16, 0, 0);
}

// ---------------------------------------------------------------------------
// pack A (fp32 [Mreal x K], rows rowOff+blk*64..) -> hi/lo bf16, fragment-major:
// elem offset = (((rowblk*KT + kt)*4 + f)*64 + lane)*8 + e
// row = rowOff + rowblk*64 + f*16 + (lane&15); k = kt*32 + (lane>>4)*8 + e
// rows >= Mreal are zero-filled. grid (nRowBlk, K/32), block 256.
// ---------------------------------------------------------------------------
__global__ __launch_bounds__(256) void pack_a_split(const float* __restrict__ src,
                                                    int Mreal, int K, int rowOff,
                                                    u16* __restrict__ Ah,
                                                    u16* __restrict__ Al) {
    __shared__ float tile[64][33];
    const int tid = threadIdx.x;
    const int rowblk = blockIdx.x;
    const int kt = blockIdx.y;
    const int KT = gridDim.y;

    {   // coalesced load 64 rows x 32 k
        const int r = tid >> 2;
        const int kq = (tid & 3) * 8;
        const int grow = rowOff + rowblk * 64 + r;
        float4 v0 = make_float4(0.f, 0.f, 0.f, 0.f), v1 = v0;
        if (grow < Mreal) {
            const float* p = src + (size_t)grow * K + kt * 32 + kq;
            v0 = *(const float4*)p;
            v1 = *(const float4*)(p + 4);
        }
        tile[r][kq + 0] = v0.x; tile[r][kq + 1] = v0.y;
        tile[r][kq + 2] = v0.z; tile[r][kq + 3] = v0.w;
        tile[r][kq + 4] = v1.x; tile[r][kq + 5] = v1.y;
        tile[r][kq + 6] = v1.z; tile[r][kq + 7] = v1.w;
    }
    __syncthreads();

    const int f = tid >> 6;
    const int lane = tid & 63;
    const int rloc = f * 16 + (lane & 15);
    const int kloc = (lane >> 4) * 8;
    bf16x8 hv, lv;
#pragma unroll
    for (int e = 0; e < 8; e++) {
        const float v = tile[rloc][kloc + e];
        const u16 h = f2bf(v);
        hv[e] = (short)h;
        lv[e] = (short)f2bf(v - bf2f(h));
    }
    const size_t off = ((((size_t)rowblk * KT + kt) * 4 + f) * 64 + lane) * 8;
    *(bf16x8*)(Ah + off) = hv;
    *(bf16x8*)(Al + off) = lv;
}

// ---------------------------------------------------------------------------
// pack B (fp32 [K x 256]) -> hi/lo, fragment-major:
// chunk g = kt*1024 + f*64 + lane; col = f*16 + (lane&15); k = kt*32+(lane>>4)*8+e
// grid = K/32*1024/256 blocks.
// ---------------------------------------------------------------------------
__global__ __launch_bounds__(256) void pack_b_split(const float* __restrict__ B, int K,
                                                    u16* __restrict__ Bh,
                                                    u16* __restrict__ Bl) {
    const int g = blockIdx.x * 256 + threadIdx.x;
    const int lane = g & 63;
    const int f = (g >> 6) & 15;
    const int kt = g >> 10;
    const int col = f * 16 + (lane & 15);
    const int k0 = kt * 32 + (lane >> 4) * 8;
    bf16x8 hv, lv;
#pragma unroll
    for (int e = 0; e < 8; e++) {
        const float v = B[(size_t)(k0 + e) * HC + col];
        const u16 h = f2bf(v);
        hv[e] = (short)h;
        lv[e] = (short)f2bf(v - bf2f(h));
    }
    const size_t off = (size_t)g * 8;
    *(bf16x8*)(Bh + off) = hv;
    *(bf16x8*)(Bl + off) = lv;
}

// ---------------------------------------------------------------------------
// Split-precision MFMA GEMM: C[64*blk + 64, 256] = A @ B
// A fragment-packed hi/lo (see pack_a_split), B fragment-packed hi/lo.
// 256 threads = 4 waves; wave w owns cols [w*64, w*64+64); 4x4 16x16 frags.
// C = Ah*Bh + Al*Bh + Ah*Bl  (~fp32 accuracy).
// ---------------------------------------------------------------------------
__global__ __launch_bounds__(256) void gemm_mfma_split(
    const u16* __restrict__ Ah, const u16* __restrict__ Al,
    const u16* __restrict__ Bh, const u16* __restrict__ Bl,
    float* __restrict__ C, int Mloc, int KT) {
    __shared__ u16 ldsA[4096];  // [0,2048): A_hi tile, [2048,4096): A_lo tile
    const int tid = threadIdx.x;
    const int wid = tid >> 6;
    const int lane = tid & 63;
    const int rowblk = blockIdx.x;

    f32x4 acc[4][4];
#pragma unroll
    for (int i = 0; i < 4; i++)
#pragma unroll
        for (int j = 0; j < 4; j++) acc[i][j] = (f32x4)0.f;

    const u16* aH = Ah + (size_t)rowblk * KT * 2048;
    const u16* aL = Al + (size_t)rowblk * KT * 2048;

    for (int kt = 0; kt < KT; kt++) {
        // stage A tile (8 KB) via global_load_lds: wave w stages fragment f=w, hi+lo
        glds16(aH + (size_t)kt * 2048 + wid * 512 + lane * 8, &ldsA[wid * 512]);
        glds16(aL + (size_t)kt * 2048 + wid * 512 + lane * 8, &ldsA[2048 + wid * 512]);

        // B fragments direct to VGPR (B is tiny, L2-resident); wave w takes f=w*4+j
        const u16* bH = Bh + ((size_t)kt * 16 + wid * 4) * 512;
        const u16* bL = Bl + ((size_t)kt * 16 + wid * 4) * 512;
        bf16x8 bh[4], bl[4];
#pragma unroll
        for (int j = 0; j < 4; j++) {
            bh[j] = *(const bf16x8*)(bH + j * 512 + lane * 8);
            bl[j] = *(const bf16x8*)(bL + j * 512 + lane * 8);
        }
        __syncthreads();  // drains vmcnt: LDS writes + B loads complete

        bf16x8 ah[4], al[4];
#pragma unroll
        for (int i = 0; i < 4; i++) {
            ah[i] = *(const bf16x8*)&ldsA[i * 512 + lane * 8];
            al[i] = *(const bf16x8*)&ldsA[2048 + i * 512 + lane * 8];
        }
#pragma unroll
        for (int i = 0; i < 4; i++)
#pragma unroll
            for (int j = 0; j < 4; j++) {
                acc[i][j] = __builtin_amdgcn_mfma_f32_16x16x32_bf16(ah[i], bh[j], acc[i][j], 0, 0, 0);
                acc[i][j] = __builtin_amdgcn_mfma_f32_16x16x32_bf16(al[i], bh[j], acc[i][j], 0, 0, 0);
                acc[i][j] = __builtin_amdgcn_mfma_f32_16x16x32_bf16(ah[i], bl[j], acc[i][j], 0, 0, 0);
            }
        __syncthreads();
    }

    // epilogue: C/D layout col = lane&15, row = (lane>>4)*4 + r
    const int r0 = rowblk * 64;
    const int colb = wid * 64 + (lane & 15);
#pragma unroll
    for (int i = 0; i < 4; i++) {
#pragma unroll
        for (int r = 0; r < 4; r++) {
            const int row = r0 + i * 16 + (lane >> 4) * 4 + r;
            if (row < Mloc) {
#pragma unroll
                for (int j = 0; j < 4; j++)
                    C[(size_t)row * HC + colb + j * 16] = acc[i][j][r];
            }
        }
    }
}

// ---------------------------------------------------------------------------
// Per-node attention coefficients
// ---------------------------------------------------------------------------
__global__ __launch_bounds__(256) void attn_coef(const float* __restrict__ h,
                                                 const float* __restrict__ att_s,
                                                 const float* __restrict__ att_d,
                                                 float* __restrict__ a_src,
                                                 float* __restrict__ a_dst) {
    const int n = blockIdx.x;
    const int tid = threadIdx.x;
    const float hv = h[(size_t)n * HC + tid];
    float p = hv * att_s[tid];
    float q = hv * att_d[tid];
#pragma unroll
    for (int m = 16; m >= 1; m >>= 1) {
        p += __shfl_xor(p, m);
        q += __shfl_xor(q, m);
    }
    if ((tid & 31) == 0) {
        a_src[n * NH + (tid >> 5)] = p;
        a_dst[n * NH + (tid >> 5)] = q;
    }
}

// ---------------------------------------------------------------------------
// CSR build
// ---------------------------------------------------------------------------
__global__ void count_deg(const int* __restrict__ dst, int E, int ET, int* __restrict__ deg) {
    const int e = blockIdx.x * blockDim.x + threadIdx.x;
    if (e >= ET) return;
    const int d = (e < E) ? dst[e] : (e - E);
    atomicAdd(&deg[d], 1);
}

__global__ __launch_bounds__(1024) void scan_deg(const int* __restrict__ deg,
                                                 int* __restrict__ row_ptr, int N) {
    __shared__ int sdata[1024];
    __shared__ int carry;
    const int tid = threadIdx.x;
    if (tid == 0) {
        carry = 0;
        row_ptr[0] = 0;
    }
    __syncthreads();
    for (int base = 0; base < N; base += 1024) {
        const int i = base + tid;
        int v = (i < N) ? deg[i] : 0;
        sdata[tid] = v;
        __syncthreads();
        for (int off = 1; off < 1024; off <<= 1) {
            int t = 0;
            if (tid >= off) t = sdata[tid - off];
            __syncthreads();
            sdata[tid] += t;
            __syncthreads();
        }
        const int inc = sdata[tid] + carry;
        if (i < N) row_ptr[i + 1] = inc;
        __syncthreads();
        if (tid == 1023) carry = inc;
        __syncthreads();
    }
}

__global__ void scatter_edges(const int* __restrict__ dst, int E, int ET,
                              const int* __restrict__ row_ptr, int* __restrict__ cursor,
                              int* __restrict__ eids) {
    const int e = blockIdx.x * blockDim.x + threadIdx.x;
    if (e >= ET) return;
    const int d = (e < E) ? dst[e] : (e - E);
    const int pos = atomicAdd(&cursor[d], 1);
    eids[row_ptr[d] + pos] = e;
}

// ---------------------------------------------------------------------------
// GAT aggregation: one block (256 threads) per destination node.
// ---------------------------------------------------------------------------
__global__ __launch_bounds__(256) void gat_aggregate(
    const float* __restrict__ h, const float* __restrict__ a_src,
    const float* __restrict__ a_dst, const int* __restrict__ row_ptr,
    const int* __restrict__ eids, const int* __restrict__ src_arr, int E,
    const float* __restrict__ bias, float* __restrict__ out) {
    const int n = blockIdx.x;
    const int tid = threadIdx.x;
    const int beg = row_ptr[n];
    const int deg = row_ptr[n + 1] - beg;

    __shared__ float red[256];
    __shared__ float mx[NH];
    __shared__ float dnm[NH];

    const int hh = tid & 7;
    const int slot = tid >> 3;
    const float ad1 = a_dst[n * NH + hh];

    float lmax = -1e30f;
    for (int j = slot; j < deg; j += 32) {
        const int e = eids[beg + j];
        const int s = (e < E) ? src_arr[e] : (e - E);
        float v = a_src[s * NH + hh] + ad1;
        v = (v > 0.f) ? v : NEG_SLOPE * v;
        lmax = fmaxf(lmax, v);
    }
    red[tid] = lmax;
    __syncthreads();
    for (int off = 128; off >= 8; off >>= 1) {
        if (tid < off) red[tid] = fmaxf(red[tid], red[tid + off]);
        __syncthreads();
    }
    if (tid < NH) mx[tid] = red[tid];
    __syncthreads();

    const float m_h = mx[hh];
    float lsum = 0.f;
    for (int j = slot; j < deg; j += 32) {
        const int e = eids[beg + j];
        const int s = (e < E) ? src_arr[e] : (e - E);
        float v = a_src[s * NH + hh] + ad1;
        v = (v > 0.f) ? v : NEG_SLOPE * v;
        lsum += __expf(v - m_h);
    }
    red[tid] = lsum;
    __syncthreads();
    for (int off = 128; off >= 8; off >>= 1) {
        if (tid < off) red[tid] += red[tid + off];
        __syncthreads();
    }
    if (tid < NH) dnm[tid] = red[tid];
    __syncthreads();

    const int h8 = tid >> 5;
    const float m2 = mx[h8];
    const float invd = 1.f / (dnm[h8] + 1e-16f);
    const float ad2 = a_dst[n * NH + h8];
    float acc = 0.f;
    for (int j = 0; j < deg; j++) {
        const int e = eids[beg + j];
        const int s = (e < E) ? src_arr[e] : (e - E);
        float v = a_src[s * NH + h8] + ad2;
        v = (v > 0.f) ? v : NEG_SLOPE * v;
        const float al = __expf(v - m2) * invd;
        acc += al * h[(size_t)s * HC + tid];
    }
    out[(size_t)n * HC + tid] = fmaxf(acc + bias[tid], 0.f);
}

// ---------------------------------------------------------------------------
// Global mean pool
// ---------------------------------------------------------------------------
__global__ __launch_bounds__(256) void pool_mean(const float* __restrict__ h,
                                                 const int* __restrict__ batch, int N,
                                                 float* __restrict__ pooled) {
    const int g = blockIdx.x;
    const int tid = threadIdx.x;
    int lo = 0, hi = N;
    while (lo < hi) {
        const int mid = (lo + hi) >> 1;
        if (batch[mid] < g) lo = mid + 1; else hi = mid;
    }
    const int start = lo;
    hi = N;
    while (lo < hi) {
        const int mid = (lo + hi) >> 1;
        if (batch[mid] < g + 1) lo = mid + 1; else hi = mid;
    }
    const int end = lo;
    float acc = 0.f;
    for (int n = start; n < end; n++) acc += h[(size_t)n * HC + tid];
    const float cnt = (float)(end - start);
    pooled[g * HC + tid] = acc / fmaxf(cnt, 1.0f);
}

// ---------------------------------------------------------------------------
// MLP head
// ---------------------------------------------------------------------------
__global__ __launch_bounds__(128) void mlp_head(const float* __restrict__ pooled,
                                                const float* __restrict__ w1,
                                                const float* __restrict__ b1,
                                                const float* __restrict__ w2,
                                                const float* __restrict__ b2,
                                                float* __restrict__ out) {
    const int g = blockIdx.x;
    const int tid = threadIdx.x;
    __shared__ float p[HC];
    p[tid] = pooled[g * HC + tid];
    p[tid + 128] = pooled[g * HC + tid + 128];
    __syncthreads();
    float z = b1[tid];
#pragma unroll 8
    for (int k = 0; k < HC; k++) z += p[k] * w1[k * 128 + tid];
    z = fmaxf(z, 0.f);
    float t = z * w2[tid];
#pragma unroll
    for (int m = 32; m >= 1; m >>= 1) t += __shfl_xor(t, m);
    __shared__ float ws2[2];
    if ((tid & 63) == 0) ws2[tid >> 6] = t;
    __syncthreads();
    if (tid == 0) out[g] = ws2[0] + ws2[1] + b2[0];
}

// ---------------------------------------------------------------------------
// Host-side launcher
// ---------------------------------------------------------------------------
extern "C" void kernel_launch(void* const* d_in, const int* in_sizes, int n_in,
                              void* d_out, int out_size, void* d_ws, size_t ws_size,
                              hipStream_t stream) {
    const float* x      = (const float*)d_in[0];
    const int*   ei     = (const int*)d_in[1];
    const int*   batch  = (const int*)d_in[2];
    const float* W1     = (const float*)d_in[3];
    const float* as1    = (const float*)d_in[4];
    const float* ad1    = (const float*)d_in[5];
    const float* b1     = (const float*)d_in[6];
    const float* W2     = (const float*)d_in[7];
    const float* as2    = (const float*)d_in[8];
    const float* ad2    = (const float*)d_in[9];
    const float* b2     = (const float*)d_in[10];
    const float* lin1w  = (const float*)d_in[11];
    const float* lin1b  = (const float*)d_in[12];
    const float* lin2w  = (const float*)d_in[13];
    const float* lin2b  = (const float*)d_in[14];

    const int N   = in_sizes[2];       // 50000
    const int E   = in_sizes[1] / 2;   // 800000
    const int ET  = E + N;
    const int Fin = in_sizes[0] / N;   // 1280
    const int NG  = 64;

    const int nRB    = (N + 63) / 64;        // 782 row-blocks of 64
    const int halfRB = (nRB + 1) / 2;        // 391
    const int rowsHalf = halfRB * 64;        // 25024
    const int KT1 = Fin / 32;                // 40
    const int KT2 = HC / 32;                 // 8

    const int* src_arr = ei;
    const int* dst_arr = ei + E;

    char* ws = (char*)d_ws;
    size_t off = 0;
    auto alloc = [&](size_t bytes) {
        void* p = ws + off;
        off += (bytes + 255) & ~(size_t)255;
        return p;
    };
    float* h_gemm  = (float*)alloc((size_t)N * HC * sizeof(float));
    float* h_agg   = (float*)alloc((size_t)N * HC * sizeof(float));
    float* a_src   = (float*)alloc((size_t)N * NH * sizeof(float));
    float* a_dst   = (float*)alloc((size_t)N * NH * sizeof(float));
    int*   deg     = (int*)alloc((size_t)N * sizeof(int));
    int*   cursor  = (int*)alloc((size_t)N * sizeof(int));
    int*   row_ptr = (int*)alloc((size_t)(N + 1) * sizeof(int));
    int*   eids    = (int*)alloc((size_t)ET * sizeof(int));
    float* pooled  = (float*)alloc((size_t)NG * HC * sizeof(float));
    // packed GEMM operands (A buffers sized for the larger of: half of layer-1 A,
    // full layer-2 A)
    size_t aElems = (size_t)rowsHalf * Fin;                 // 25024*1280
    const size_t a2Elems = (size_t)nRB * 64 * HC;           // 50048*256
    if (a2Elems > aElems) aElems = a2Elems;
    u16* Ah = (u16*)alloc(aElems * sizeof(u16));
    u16* Al = (u16*)alloc(aElems * sizeof(u16));
    u16* Bh = (u16*)alloc((size_t)Fin * HC * sizeof(u16));
    u16* Bl = (u16*)alloc((size_t)Fin * HC * sizeof(u16));
    (void)ws_size; (void)n_in; (void)out_size;

    // ---- CSR build ----
    hipMemsetAsync(deg, 0, (size_t)N * sizeof(int), stream);
    hipMemsetAsync(cursor, 0, (size_t)N * sizeof(int), stream);
    {
        const int blocks = (ET + 255) / 256;
        count_deg<<<blocks, 256, 0, stream>>>(dst_arr, E, ET, deg);
        scan_deg<<<1, 1024, 0, stream>>>(deg, row_ptr, N);
        scatter_edges<<<blocks, 256, 0, stream>>>(dst_arr, E, ET, row_ptr, cursor, eids);
    }

    // ---- Layer 1: GEMM (split-precision MFMA, two row-halves) ----
    pack_b_split<<<KT1 * 4, 256, 0, stream>>>(W1, Fin, Bh, Bl);
    for (int half = 0; half < 2; half++) {
        const int rb = (half == 0) ? halfRB : (nRB - halfRB);
        pack_a_split<<<dim3(rb, KT1), 256, 0, stream>>>(x, N, Fin, half * rowsHalf, Ah, Al);
        const int mloc = N - half * rowsHalf < rowsHalf ? N - half * rowsHalf : rowsHalf;
        gemm_mfma_split<<<rb, 256, 0, stream>>>(Ah, Al, Bh, Bl,
                                                h_gemm + (size_t)half * rowsHalf * HC,
                                                mloc, KT1);
    }
    attn_coef<<<N, 256, 0, stream>>>(h_gemm, as1, ad1, a_src, a_dst);
    gat_aggregate<<<N, 256, 0, stream>>>(h_gemm, a_src, a_dst, row_ptr, eids, src_arr, E,
                                         b1, h_agg);

    // ---- Layer 2 ----
    pack_b_split<<<KT2 * 4, 256, 0, stream>>>(W2, HC, Bh, Bl);
    pack_a_split<<<dim3(nRB, KT2), 256, 0, stream>>>(h_agg, N, HC, 0, Ah, Al);
    gemm_mfma_split<<<nRB, 256, 0, stream>>>(Ah, Al, Bh, Bl, h_gemm, N, KT2);
    attn_coef<<<N, 256, 0, stream>>>(h_gemm, as2, ad2, a_src, a_dst);
    gat_aggregate<<<N, 256, 0, stream>>>(h_gemm, a_src, a_dst, row_ptr, eids, src_arr, E,
                                         b2, h_agg);

    // ---- Pool + MLP head ----
    pool_mean<<<NG, 256, 0, stream>>>(h_agg, batch, N, pooled);
    mlp_head<<<NG, 128, 0, stream>>>(pooled, lin1w, lin1b, lin2w, lin2b, (float*)d_out);
}

// Round 3
// 919.502 us; speedup vs baseline: 1.8456x; 1.4316x over previous
//
#include <hip/hip_runtime.h>
#include <hip/hip_bf16.h>
#include <math.h>

#define HC 256
#define NH 8
#define NEG_SLOPE 0.2f
#define CH 256   // edge chunk per aggregation block

typedef unsigned short u16;
typedef __attribute__((ext_vector_type(8))) short bf16x8;
typedef __attribute__((ext_vector_type(4))) float f32x4;

__device__ __forceinline__ u16 f2bf(float f) {
    unsigned int u = __float_as_uint(f);
    u += 0x7FFFu + ((u >> 16) & 1u);
    return (u16)(u >> 16);
}
__device__ __forceinline__ float bf2f(u16 s) {
    return __uint_as_float(((unsigned int)s) << 16);
}

__device__ __forceinline__ void glds16(const u16* g, u16* l) {
    __builtin_amdgcn_global_load_lds(
        (const __attribute__((address_space(1))) void*)g,
        (__attribute__((address_space(3))) void*)l, 16, 0, 0);
}

// ---------------------------------------------------------------------------
// pack A (fp32 [Mreal x K], rows rowOff+blk*64..) -> hi/lo bf16, fragment-major
// ---------------------------------------------------------------------------
__global__ __launch_bounds__(256) void pack_a_split(const float* __restrict__ src,
                                                    int Mreal, int K, int rowOff,
                                                    u16* __restrict__ Ah,
                                                    u16* __restrict__ Al) {
    __shared__ float tile[64][33];
    const int tid = threadIdx.x;
    const int rowblk = blockIdx.x;
    const int kt = blockIdx.y;
    const int KT = gridDim.y;

    {
        const int r = tid >> 2;
        const int kq = (tid & 3) * 8;
        const int grow = rowOff + rowblk * 64 + r;
        float4 v0 = make_float4(0.f, 0.f, 0.f, 0.f), v1 = v0;
        if (grow < Mreal) {
            const float* p = src + (size_t)grow * K + kt * 32 + kq;
            v0 = *(const float4*)p;
            v1 = *(const float4*)(p + 4);
        }
        tile[r][kq + 0] = v0.x; tile[r][kq + 1] = v0.y;
        tile[r][kq + 2] = v0.z; tile[r][kq + 3] = v0.w;
        tile[r][kq + 4] = v1.x; tile[r][kq + 5] = v1.y;
        tile[r][kq + 6] = v1.z; tile[r][kq + 7] = v1.w;
    }
    __syncthreads();

    const int f = tid >> 6;
    const int lane = tid & 63;
    const int rloc = f * 16 + (lane & 15);
    const int kloc = (lane >> 4) * 8;
    bf16x8 hv, lv;
#pragma unroll
    for (int e = 0; e < 8; e++) {
        const float v = tile[rloc][kloc + e];
        const u16 h = f2bf(v);
        hv[e] = (short)h;
        lv[e] = (short)f2bf(v - bf2f(h));
    }
    const size_t off = ((((size_t)rowblk * KT + kt) * 4 + f) * 64 + lane) * 8;
    *(bf16x8*)(Ah + off) = hv;
    *(bf16x8*)(Al + off) = lv;
}

// ---------------------------------------------------------------------------
// pack B (fp32 [K x 256]) -> hi/lo, fragment-major
// ---------------------------------------------------------------------------
__global__ __launch_bounds__(256) void pack_b_split(const float* __restrict__ B, int K,
                                                    u16* __restrict__ Bh,
                                                    u16* __restrict__ Bl) {
    const int g = blockIdx.x * 256 + threadIdx.x;
    const int lane = g & 63;
    const int f = (g >> 6) & 15;
    const int kt = g >> 10;
    const int col = f * 16 + (lane & 15);
    const int k0 = kt * 32 + (lane >> 4) * 8;
    bf16x8 hv, lv;
#pragma unroll
    for (int e = 0; e < 8; e++) {
        const float v = B[(size_t)(k0 + e) * HC + col];
        const u16 h = f2bf(v);
        hv[e] = (short)h;
        lv[e] = (short)f2bf(v - bf2f(h));
    }
    const size_t off = (size_t)g * 8;
    *(bf16x8*)(Bh + off) = hv;
    *(bf16x8*)(Bl + off) = lv;
}

// ---------------------------------------------------------------------------
// Split-precision MFMA GEMM
// ---------------------------------------------------------------------------
__global__ __launch_bounds__(256) void gemm_mfma_split(
    const u16* __restrict__ Ah, const u16* __restrict__ Al,
    const u16* __restrict__ Bh, const u16* __restrict__ Bl,
    float* __restrict__ C, int Mloc, int KT) {
    __shared__ u16 ldsA[4096];
    const int tid = threadIdx.x;
    const int wid = tid >> 6;
    const int lane = tid & 63;
    const int rowblk = blockIdx.x;

    f32x4 acc[4][4];
#pragma unroll
    for (int i = 0; i < 4; i++)
#pragma unroll
        for (int j = 0; j < 4; j++) acc[i][j] = (f32x4)0.f;

    const u16* aH = Ah + (size_t)rowblk * KT * 2048;
    const u16* aL = Al + (size_t)rowblk * KT * 2048;

    for (int kt = 0; kt < KT; kt++) {
        glds16(aH + (size_t)kt * 2048 + wid * 512 + lane * 8, &ldsA[wid * 512]);
        glds16(aL + (size_t)kt * 2048 + wid * 512 + lane * 8, &ldsA[2048 + wid * 512]);

        const u16* bH = Bh + ((size_t)kt * 16 + wid * 4) * 512;
        const u16* bL = Bl + ((size_t)kt * 16 + wid * 4) * 512;
        bf16x8 bh[4], bl[4];
#pragma unroll
        for (int j = 0; j < 4; j++) {
            bh[j] = *(const bf16x8*)(bH + j * 512 + lane * 8);
            bl[j] = *(const bf16x8*)(bL + j * 512 + lane * 8);
        }
        __syncthreads();

        bf16x8 ah[4], al[4];
#pragma unroll
        for (int i = 0; i < 4; i++) {
            ah[i] = *(const bf16x8*)&ldsA[i * 512 + lane * 8];
            al[i] = *(const bf16x8*)&ldsA[2048 + i * 512 + lane * 8];
        }
#pragma unroll
        for (int i = 0; i < 4; i++)
#pragma unroll
            for (int j = 0; j < 4; j++) {
                acc[i][j] = __builtin_amdgcn_mfma_f32_16x16x32_bf16(ah[i], bh[j], acc[i][j], 0, 0, 0);
                acc[i][j] = __builtin_amdgcn_mfma_f32_16x16x32_bf16(al[i], bh[j], acc[i][j], 0, 0, 0);
                acc[i][j] = __builtin_amdgcn_mfma_f32_16x16x32_bf16(ah[i], bl[j], acc[i][j], 0, 0, 0);
            }
        __syncthreads();
    }

    const int r0 = rowblk * 64;
    const int colb = wid * 64 + (lane & 15);
#pragma unroll
    for (int i = 0; i < 4; i++) {
#pragma unroll
        for (int r = 0; r < 4; r++) {
            const int row = r0 + i * 16 + (lane >> 4) * 4 + r;
            if (row < Mloc) {
#pragma unroll
                for (int j = 0; j < 4; j++)
                    C[(size_t)row * HC + colb + j * 16] = acc[i][j][r];
            }
        }
    }
}

// ---------------------------------------------------------------------------
// Per-node attention coefficients
// ---------------------------------------------------------------------------
__global__ __launch_bounds__(256) void attn_coef(const float* __restrict__ h,
                                                 const float* __restrict__ att_s,
                                                 const float* __restrict__ att_d,
                                                 float* __restrict__ a_src,
                                                 float* __restrict__ a_dst) {
    const int n = blockIdx.x;
    const int tid = threadIdx.x;
    const float hv = h[(size_t)n * HC + tid];
    float p = hv * att_s[tid];
    float q = hv * att_d[tid];
#pragma unroll
    for (int m = 16; m >= 1; m >>= 1) {
        p += __shfl_xor(p, m);
        q += __shfl_xor(q, m);
    }
    if ((tid & 31) == 0) {
        a_src[n * NH + (tid >> 5)] = p;
        a_dst[n * NH + (tid >> 5)] = q;
    }
}

// ---------------------------------------------------------------------------
// CSR build: count, two-level scan, scatter
// ---------------------------------------------------------------------------
__global__ void count_deg(const int* __restrict__ dst, int E, int ET, int* __restrict__ deg) {
    const int e = blockIdx.x * blockDim.x + threadIdx.x;
    if (e >= ET) return;
    const int d = (e < E) ? dst[e] : (e - E);
    atomicAdd(&deg[d], 1);
}

// block b scans deg[b*1024 .. b*1024+1023] (inclusive) into row_ptr[+1],
// writes block total to partials[b]. 256 threads, 4 elems each.
__global__ __launch_bounds__(256) void scan_block(const int* __restrict__ deg,
                                                  int* __restrict__ row_ptr,
                                                  int* __restrict__ partials, int N) {
    __shared__ int sd[256];
    const int tid = threadIdx.x;
    const int base = blockIdx.x * 1024 + tid * 4;
    int v0 = (base + 0 < N) ? deg[base + 0] : 0;
    int v1 = (base + 1 < N) ? deg[base + 1] : 0;
    int v2 = (base + 2 < N) ? deg[base + 2] : 0;
    int v3 = (base + 3 < N) ? deg[base + 3] : 0;
    const int tsum = v0 + v1 + v2 + v3;
    sd[tid] = tsum;
    __syncthreads();
    int run = tsum;
    for (int off = 1; off < 256; off <<= 1) {
        int t = 0;
        if (tid >= off) t = sd[tid - off];
        __syncthreads();
        run += t;
        sd[tid] = run;
        __syncthreads();
    }
    const int excl = run - tsum;
    int s0 = excl + v0, s1 = s0 + v1, s2 = s1 + v2, s3 = s2 + v3;
    if (base + 0 < N) row_ptr[base + 1] = s0;
    if (base + 1 < N) row_ptr[base + 2] = s1;
    if (base + 2 < N) row_ptr[base + 3] = s2;
    if (base + 3 < N) row_ptr[base + 4] = s3;
    if (tid == 255) partials[blockIdx.x] = run;
}

// single block: exclusive-scan partials[0..nb) in place (nb <= 1024)
__global__ __launch_bounds__(1024) void scan_partials(int* __restrict__ partials, int nb) {
    __shared__ int sd[1024];
    const int tid = threadIdx.x;
    int v = (tid < nb) ? partials[tid] : 0;
    sd[tid] = v;
    __syncthreads();
    int run = v;
    for (int off = 1; off < 1024; off <<= 1) {
        int t = 0;
        if (tid >= off) t = sd[tid - off];
        __syncthreads();
        run += t;
        sd[tid] = run;
        __syncthreads();
    }
    if (tid < nb) partials[tid] = run - v;  // exclusive
}

__global__ __launch_bounds__(256) void scan_add(int* __restrict__ row_ptr,
                                                const int* __restrict__ partials, int N) {
    const int i = blockIdx.x * 256 + threadIdx.x;  // element i -> row_ptr[i+1]
    if (i == 0) row_ptr[0] = 0;
    if (i < N) row_ptr[i + 1] += partials[i >> 10];
}

__global__ void scatter_edges(const int* __restrict__ dst, int E, int ET,
                              const int* __restrict__ row_ptr, int* __restrict__ cursor,
                              int* __restrict__ eids) {
    const int e = blockIdx.x * blockDim.x + threadIdx.x;
    if (e >= ET) return;
    const int d = (e < E) ? dst[e] : (e - E);
    const int pos = atomicAdd(&cursor[d], 1);
    eids[row_ptr[d] + pos] = e;
}

// ---------------------------------------------------------------------------
// GAT aggregation, chunked online-softmax. One block = one dst node.
// Phase 1: thread j computes all 8 head e-values for edge j once -> LDS.
// Phase 2: per-head chunk max (shuffle), merge with running max, scale.
// Phase 3: p = exp(ev - m) in LDS, per-head chunk sum, merge denom.
// Phase 4: gather h[src] (only global load) weighted by LDS alpha, unroll x4.
// ---------------------------------------------------------------------------
__global__ __launch_bounds__(256) void gat_aggregate(
    const float* __restrict__ h, const float* __restrict__ a_src,
    const float* __restrict__ a_dst, const int* __restrict__ row_ptr,
    const int* __restrict__ eids, const int* __restrict__ src_arr, int E,
    const float* __restrict__ bias, float* __restrict__ out) {
    const int n = blockIdx.x;
    const int tid = threadIdx.x;
    const int beg = row_ptr[n];
    const int deg = row_ptr[n + 1] - beg;

    __shared__ int   srcs[CH];
    __shared__ float ev[CH][NH];
    __shared__ float red[32];
    __shared__ float mxs[NH], scl[NH];
    __shared__ float m_run[NH], d_run[NH];

    if (tid < NH) { m_run[tid] = -1e30f; d_run[tid] = 0.f; }

    const int hh = tid & 7;      // head lane for reductions
    const int slot = tid >> 3;   // 0..31
    const int h8 = tid >> 5;     // head for accumulation (feature tid)
    float acc = 0.f;

    for (int c0 = 0; c0 < deg; c0 += CH) {
        const int chlen = min(CH, deg - c0);
        __syncthreads();  // previous phase-4 reads done; also covers init

        // ---- phase 1: per-edge e-values (once) ----
        if (tid < chlen) {
            const int e = eids[beg + c0 + tid];
            const int s = (e < E) ? src_arr[e] : (e - E);
            srcs[tid] = s;
            const float4 as0 = *(const float4*)&a_src[s * NH];
            const float4 as1 = *(const float4*)&a_src[s * NH + 4];
            const float4 ad0 = *(const float4*)&a_dst[n * NH];
            const float4 ad1 = *(const float4*)&a_dst[n * NH + 4];
            float4 w0, w1;
            w0.x = as0.x + ad0.x; w0.y = as0.y + ad0.y;
            w0.z = as0.z + ad0.z; w0.w = as0.w + ad0.w;
            w1.x = as1.x + ad1.x; w1.y = as1.y + ad1.y;
            w1.z = as1.z + ad1.z; w1.w = as1.w + ad1.w;
            w0.x = w0.x > 0.f ? w0.x : NEG_SLOPE * w0.x;
            w0.y = w0.y > 0.f ? w0.y : NEG_SLOPE * w0.y;
            w0.z = w0.z > 0.f ? w0.z : NEG_SLOPE * w0.z;
            w0.w = w0.w > 0.f ? w0.w : NEG_SLOPE * w0.w;
            w1.x = w1.x > 0.f ? w1.x : NEG_SLOPE * w1.x;
            w1.y = w1.y > 0.f ? w1.y : NEG_SLOPE * w1.y;
            w1.z = w1.z > 0.f ? w1.z : NEG_SLOPE * w1.z;
            w1.w = w1.w > 0.f ? w1.w : NEG_SLOPE * w1.w;
            *(float4*)&ev[tid][0] = w0;
            *(float4*)&ev[tid][4] = w1;
        }
        __syncthreads();

        // ---- phase 2: per-head chunk max ----
        float lmax = -1e30f;
        for (int j = slot; j < chlen; j += 32) lmax = fmaxf(lmax, ev[j][hh]);
        lmax = fmaxf(lmax, __shfl_xor(lmax, 8));
        lmax = fmaxf(lmax, __shfl_xor(lmax, 16));
        lmax = fmaxf(lmax, __shfl_xor(lmax, 32));
        if ((tid & 63) < 8) red[(tid >> 6) * 8 + hh] = lmax;  // lane 0..7: hh==lane
        __syncthreads();
        if (tid < NH) {
            float mn = fmaxf(fmaxf(red[tid], red[8 + tid]),
                             fmaxf(red[16 + tid], red[24 + tid]));
            const float mo = m_run[tid];
            mn = fmaxf(mo, mn);
            m_run[tid] = mn;
            mxs[tid] = mn;
            scl[tid] = __expf(mo - mn);
        }
        __syncthreads();

        // ---- phase 3: exp + per-head chunk sum ----
        const float mh = mxs[hh];
        float lsum = 0.f;
        for (int j = slot; j < chlen; j += 32) {
            const float p = __expf(ev[j][hh] - mh);
            ev[j][hh] = p;
            lsum += p;
        }
        lsum += __shfl_xor(lsum, 8);
        lsum += __shfl_xor(lsum, 16);
        lsum += __shfl_xor(lsum, 32);
        if ((tid & 63) < 8) red[(tid >> 6) * 8 + hh] = lsum;
        __syncthreads();
        if (tid < NH)
            d_run[tid] = d_run[tid] * scl[tid] +
                         ((red[tid] + red[8 + tid]) + (red[16 + tid] + red[24 + tid]));
        __syncthreads();

        // ---- phase 4: weighted gather ----
        float t0 = 0.f, t1 = 0.f, t2 = 0.f, t3 = 0.f;
        int j = 0;
        for (; j + 4 <= chlen; j += 4) {
            const int s0 = srcs[j], s1 = srcs[j + 1], s2 = srcs[j + 2], s3 = srcs[j + 3];
            const float p0 = ev[j][h8], p1 = ev[j + 1][h8];
            const float p2 = ev[j + 2][h8], p3 = ev[j + 3][h8];
            t0 += p0 * h[(size_t)s0 * HC + tid];
            t1 += p1 * h[(size_t)s1 * HC + tid];
            t2 += p2 * h[(size_t)s2 * HC + tid];
            t3 += p3 * h[(size_t)s3 * HC + tid];
        }
        for (; j < chlen; j++) t0 += ev[j][h8] * h[(size_t)srcs[j] * HC + tid];
        acc = acc * scl[h8] + ((t0 + t1) + (t2 + t3));
    }

    const float invd = 1.f / (d_run[h8] + 1e-16f);
    out[(size_t)n * HC + tid] = fmaxf(acc * invd + bias[tid], 0.f);
}

// ---------------------------------------------------------------------------
// Global mean pool
// ---------------------------------------------------------------------------
__global__ __launch_bounds__(256) void pool_mean(const float* __restrict__ h,
                                                 const int* __restrict__ batch, int N,
                                                 float* __restrict__ pooled) {
    const int g = blockIdx.x;
    const int tid = threadIdx.x;
    int lo = 0, hi = N;
    while (lo < hi) {
        const int mid = (lo + hi) >> 1;
        if (batch[mid] < g) lo = mid + 1; else hi = mid;
    }
    const int start = lo;
    hi = N;
    while (lo < hi) {
        const int mid = (lo + hi) >> 1;
        if (batch[mid] < g + 1) lo = mid + 1; else hi = mid;
    }
    const int end = lo;
    float acc = 0.f;
    for (int n = start; n < end; n++) acc += h[(size_t)n * HC + tid];
    const float cnt = (float)(end - start);
    pooled[g * HC + tid] = acc / fmaxf(cnt, 1.0f);
}

// ---------------------------------------------------------------------------
// MLP head
// ---------------------------------------------------------------------------
__global__ __launch_bounds__(128) void mlp_head(const float* __restrict__ pooled,
                                                const float* __restrict__ w1,
                                                const float* __restrict__ b1,
                                                const float* __restrict__ w2,
                                                const float* __restrict__ b2,
                                                float* __restrict__ out) {
    const int g = blockIdx.x;
    const int tid = threadIdx.x;
    __shared__ float p[HC];
    p[tid] = pooled[g * HC + tid];
    p[tid + 128] = pooled[g * HC + tid + 128];
    __syncthreads();
    float z = b1[tid];
#pragma unroll 8
    for (int k = 0; k < HC; k++) z += p[k] * w1[k * 128 + tid];
    z = fmaxf(z, 0.f);
    float t = z * w2[tid];
#pragma unroll
    for (int m = 32; m >= 1; m >>= 1) t += __shfl_xor(t, m);
    __shared__ float ws2[2];
    if ((tid & 63) == 0) ws2[tid >> 6] = t;
    __syncthreads();
    if (tid == 0) out[g] = ws2[0] + ws2[1] + b2[0];
}

// ---------------------------------------------------------------------------
// Host-side launcher
// ---------------------------------------------------------------------------
extern "C" void kernel_launch(void* const* d_in, const int* in_sizes, int n_in,
                              void* d_out, int out_size, void* d_ws, size_t ws_size,
                              hipStream_t stream) {
    const float* x      = (const float*)d_in[0];
    const int*   ei     = (const int*)d_in[1];
    const int*   batch  = (const int*)d_in[2];
    const float* W1     = (const float*)d_in[3];
    const float* as1    = (const float*)d_in[4];
    const float* ad1    = (const float*)d_in[5];
    const float* b1     = (const float*)d_in[6];
    const float* W2     = (const float*)d_in[7];
    const float* as2    = (const float*)d_in[8];
    const float* ad2    = (const float*)d_in[9];
    const float* b2     = (const float*)d_in[10];
    const float* lin1w  = (const float*)d_in[11];
    const float* lin1b  = (const float*)d_in[12];
    const float* lin2w  = (const float*)d_in[13];
    const float* lin2b  = (const float*)d_in[14];

    const int N   = in_sizes[2];       // 50000
    const int E   = in_sizes[1] / 2;   // 800000
    const int ET  = E + N;
    const int Fin = in_sizes[0] / N;   // 1280
    const int NG  = 64;

    const int nRB    = (N + 63) / 64;
    const int halfRB = (nRB + 1) / 2;
    const int rowsHalf = halfRB * 64;
    const int KT1 = Fin / 32;
    const int KT2 = HC / 32;
    const int nScanBlk = (N + 1023) / 1024;

    const int* src_arr = ei;
    const int* dst_arr = ei + E;

    char* ws = (char*)d_ws;
    size_t off = 0;
    auto alloc = [&](size_t bytes) {
        void* p = ws + off;
        off += (bytes + 255) & ~(size_t)255;
        return p;
    };
    float* h_gemm  = (float*)alloc((size_t)N * HC * sizeof(float));
    float* h_agg   = (float*)alloc((size_t)N * HC * sizeof(float));
    float* a_src   = (float*)alloc((size_t)N * NH * sizeof(float));
    float* a_dst   = (float*)alloc((size_t)N * NH * sizeof(float));
    int*   deg     = (int*)alloc((size_t)N * sizeof(int));
    int*   cursor  = (int*)alloc((size_t)N * sizeof(int));
    int*   row_ptr = (int*)alloc((size_t)(N + 1) * sizeof(int));
    int*   partials= (int*)alloc((size_t)1024 * sizeof(int));
    int*   eids    = (int*)alloc((size_t)ET * sizeof(int));
    float* pooled  = (float*)alloc((size_t)NG * HC * sizeof(float));
    size_t aElems = (size_t)rowsHalf * Fin;
    const size_t a2Elems = (size_t)nRB * 64 * HC;
    if (a2Elems > aElems) aElems = a2Elems;
    u16* Ah = (u16*)alloc(aElems * sizeof(u16));
    u16* Al = (u16*)alloc(aElems * sizeof(u16));
    u16* Bh = (u16*)alloc((size_t)Fin * HC * sizeof(u16));
    u16* Bl = (u16*)alloc((size_t)Fin * HC * sizeof(u16));
    (void)ws_size; (void)n_in; (void)out_size;

    // ---- CSR build ----
    hipMemsetAsync(deg, 0, (size_t)N * sizeof(int), stream);
    hipMemsetAsync(cursor, 0, (size_t)N * sizeof(int), stream);
    {
        const int blocks = (ET + 255) / 256;
        count_deg<<<blocks, 256, 0, stream>>>(dst_arr, E, ET, deg);
        scan_block<<<nScanBlk, 256, 0, stream>>>(deg, row_ptr, partials, N);
        scan_partials<<<1, 1024, 0, stream>>>(partials, nScanBlk);
        scan_add<<<(N + 255) / 256, 256, 0, stream>>>(row_ptr, partials, N);
        scatter_edges<<<blocks, 256, 0, stream>>>(dst_arr, E, ET, row_ptr, cursor, eids);
    }

    // ---- Layer 1 ----
    pack_b_split<<<KT1 * 4, 256, 0, stream>>>(W1, Fin, Bh, Bl);
    for (int half = 0; half < 2; half++) {
        const int rb = (half == 0) ? halfRB : (nRB - halfRB);
        pack_a_split<<<dim3(rb, KT1), 256, 0, stream>>>(x, N, Fin, half * rowsHalf, Ah, Al);
        const int mloc = N - half * rowsHalf < rowsHalf ? N - half * rowsHalf : rowsHalf;
        gemm_mfma_split<<<rb, 256, 0, stream>>>(Ah, Al, Bh, Bl,
                                                h_gemm + (size_t)half * rowsHalf * HC,
                                                mloc, KT1);
    }
    attn_coef<<<N, 256, 0, stream>>>(h_gemm, as1, ad1, a_src, a_dst);
    gat_aggregate<<<N, 256, 0, stream>>>(h_gemm, a_src, a_dst, row_ptr, eids, src_arr, E,
                                         b1, h_agg);

    // ---- Layer 2 ----
    pack_b_split<<<KT2 * 4, 256, 0, stream>>>(W2, HC, Bh, Bl);
    pack_a_split<<<dim3(nRB, KT2), 256, 0, stream>>>(h_agg, N, HC, 0, Ah, Al);
    gemm_mfma_split<<<nRB, 256, 0, stream>>>(Ah, Al, Bh, Bl, h_gemm, N, KT2);
    attn_coef<<<N, 256, 0, stream>>>(h_gemm, as2, ad2, a_src, a_dst);
    gat_aggregate<<<N, 256, 0, stream>>>(h_gemm, a_src, a_dst, row_ptr, eids, src_arr, E,
                                         b2, h_agg);

    // ---- Pool + MLP head ----
    pool_mean<<<NG, 256, 0, stream>>>(h_agg, batch, N, pooled);
    mlp_head<<<NG, 128, 0, stream>>>(pooled, lin1w, lin1b, lin2w, lin2b, (float*)d_out);
}

// Round 4
// 743.496 us; speedup vs baseline: 2.2826x; 1.2367x over previous
//
#include <hip/hip_runtime.h>
#include <hip/hip_bf16.h>
#include <math.h>

#define HC 256
#define NH 8
#define NEG_SLOPE 0.2f
#define CH 256   // edge chunk per aggregation block

typedef unsigned short u16;
typedef __attribute__((ext_vector_type(8))) short bf16x8;
typedef __attribute__((ext_vector_type(4))) float f32x4;

__device__ __forceinline__ u16 f2bf(float f) {
    unsigned int u = __float_as_uint(f);
    u += 0x7FFFu + ((u >> 16) & 1u);
    return (u16)(u >> 16);
}
__device__ __forceinline__ float bf2f(u16 s) {
    return __uint_as_float(((unsigned int)s) << 16);
}

__device__ __forceinline__ void glds16(const u16* g, u16* l) {
    __builtin_amdgcn_global_load_lds(
        (const __attribute__((address_space(1))) void*)g,
        (__attribute__((address_space(3))) void*)l, 16, 0, 0);
}

// ---------------------------------------------------------------------------
// pack A (fp32 [Mreal x K], rows rowOff+blk*64..) -> hi/lo bf16, fragment-major
// ---------------------------------------------------------------------------
__global__ __launch_bounds__(256) void pack_a_split(const float* __restrict__ src,
                                                    int Mreal, int K, int rowOff,
                                                    u16* __restrict__ Ah,
                                                    u16* __restrict__ Al) {
    __shared__ float tile[64][33];
    const int tid = threadIdx.x;
    const int rowblk = blockIdx.x;
    const int kt = blockIdx.y;
    const int KT = gridDim.y;

    {
        const int r = tid >> 2;
        const int kq = (tid & 3) * 8;
        const int grow = rowOff + rowblk * 64 + r;
        float4 v0 = make_float4(0.f, 0.f, 0.f, 0.f), v1 = v0;
        if (grow < Mreal) {
            const float* p = src + (size_t)grow * K + kt * 32 + kq;
            v0 = *(const float4*)p;
            v1 = *(const float4*)(p + 4);
        }
        tile[r][kq + 0] = v0.x; tile[r][kq + 1] = v0.y;
        tile[r][kq + 2] = v0.z; tile[r][kq + 3] = v0.w;
        tile[r][kq + 4] = v1.x; tile[r][kq + 5] = v1.y;
        tile[r][kq + 6] = v1.z; tile[r][kq + 7] = v1.w;
    }
    __syncthreads();

    const int f = tid >> 6;
    const int lane = tid & 63;
    const int rloc = f * 16 + (lane & 15);
    const int kloc = (lane >> 4) * 8;
    bf16x8 hv, lv;
#pragma unroll
    for (int e = 0; e < 8; e++) {
        const float v = tile[rloc][kloc + e];
        const u16 h = f2bf(v);
        hv[e] = (short)h;
        lv[e] = (short)f2bf(v - bf2f(h));
    }
    const size_t off = ((((size_t)rowblk * KT + kt) * 4 + f) * 64 + lane) * 8;
    *(bf16x8*)(Ah + off) = hv;
    *(bf16x8*)(Al + off) = lv;
}

// ---------------------------------------------------------------------------
// pack B (fp32 [K x 256]) -> hi/lo, fragment-major
// ---------------------------------------------------------------------------
__global__ __launch_bounds__(256) void pack_b_split(const float* __restrict__ B, int K,
                                                    u16* __restrict__ Bh,
                                                    u16* __restrict__ Bl) {
    const int g = blockIdx.x * 256 + threadIdx.x;
    const int lane = g & 63;
    const int f = (g >> 6) & 15;
    const int kt = g >> 10;
    const int col = f * 16 + (lane & 15);
    const int k0 = kt * 32 + (lane >> 4) * 8;
    bf16x8 hv, lv;
#pragma unroll
    for (int e = 0; e < 8; e++) {
        const float v = B[(size_t)(k0 + e) * HC + col];
        const u16 h = f2bf(v);
        hv[e] = (short)h;
        lv[e] = (short)f2bf(v - bf2f(h));
    }
    const size_t off = (size_t)g * 8;
    *(bf16x8*)(Bh + off) = hv;
    *(bf16x8*)(Bl + off) = lv;
}

// ---------------------------------------------------------------------------
// Split-precision MFMA GEMM
// ---------------------------------------------------------------------------
__global__ __launch_bounds__(256) void gemm_mfma_split(
    const u16* __restrict__ Ah, const u16* __restrict__ Al,
    const u16* __restrict__ Bh, const u16* __restrict__ Bl,
    float* __restrict__ C, int Mloc, int KT) {
    __shared__ u16 ldsA[4096];
    const int tid = threadIdx.x;
    const int wid = tid >> 6;
    const int lane = tid & 63;
    const int rowblk = blockIdx.x;

    f32x4 acc[4][4];
#pragma unroll
    for (int i = 0; i < 4; i++)
#pragma unroll
        for (int j = 0; j < 4; j++) acc[i][j] = (f32x4)0.f;

    const u16* aH = Ah + (size_t)rowblk * KT * 2048;
    const u16* aL = Al + (size_t)rowblk * KT * 2048;

    for (int kt = 0; kt < KT; kt++) {
        glds16(aH + (size_t)kt * 2048 + wid * 512 + lane * 8, &ldsA[wid * 512]);
        glds16(aL + (size_t)kt * 2048 + wid * 512 + lane * 8, &ldsA[2048 + wid * 512]);

        const u16* bH = Bh + ((size_t)kt * 16 + wid * 4) * 512;
        const u16* bL = Bl + ((size_t)kt * 16 + wid * 4) * 512;
        bf16x8 bh[4], bl[4];
#pragma unroll
        for (int j = 0; j < 4; j++) {
            bh[j] = *(const bf16x8*)(bH + j * 512 + lane * 8);
            bl[j] = *(const bf16x8*)(bL + j * 512 + lane * 8);
        }
        __syncthreads();

        bf16x8 ah[4], al[4];
#pragma unroll
        for (int i = 0; i < 4; i++) {
            ah[i] = *(const bf16x8*)&ldsA[i * 512 + lane * 8];
            al[i] = *(const bf16x8*)&ldsA[2048 + i * 512 + lane * 8];
        }
#pragma unroll
        for (int i = 0; i < 4; i++)
#pragma unroll
            for (int j = 0; j < 4; j++) {
                acc[i][j] = __builtin_amdgcn_mfma_f32_16x16x32_bf16(ah[i], bh[j], acc[i][j], 0, 0, 0);
                acc[i][j] = __builtin_amdgcn_mfma_f32_16x16x32_bf16(al[i], bh[j], acc[i][j], 0, 0, 0);
                acc[i][j] = __builtin_amdgcn_mfma_f32_16x16x32_bf16(ah[i], bl[j], acc[i][j], 0, 0, 0);
            }
        __syncthreads();
    }

    const int r0 = rowblk * 64;
    const int colb = wid * 64 + (lane & 15);
#pragma unroll
    for (int i = 0; i < 4; i++) {
#pragma unroll
        for (int r = 0; r < 4; r++) {
            const int row = r0 + i * 16 + (lane >> 4) * 4 + r;
            if (row < Mloc) {
#pragma unroll
                for (int j = 0; j < 4; j++)
                    C[(size_t)row * HC + colb + j * 16] = acc[i][j][r];
            }
        }
    }
}

// ---------------------------------------------------------------------------
// Per-node attention coefficients
// ---------------------------------------------------------------------------
__global__ __launch_bounds__(256) void attn_coef(const float* __restrict__ h,
                                                 const float* __restrict__ att_s,
                                                 const float* __restrict__ att_d,
                                                 float* __restrict__ a_src,
                                                 float* __restrict__ a_dst) {
    const int n = blockIdx.x;
    const int tid = threadIdx.x;
    const float hv = h[(size_t)n * HC + tid];
    float p = hv * att_s[tid];
    float q = hv * att_d[tid];
#pragma unroll
    for (int m = 16; m >= 1; m >>= 1) {
        p += __shfl_xor(p, m);
        q += __shfl_xor(q, m);
    }
    if ((tid & 31) == 0) {
        a_src[n * NH + (tid >> 5)] = p;
        a_dst[n * NH + (tid >> 5)] = q;
    }
}

// ---------------------------------------------------------------------------
// CSR build: count, two-level scan, scatter
// ---------------------------------------------------------------------------
__global__ void count_deg(const int* __restrict__ dst, int E, int ET, int* __restrict__ deg) {
    const int e = blockIdx.x * blockDim.x + threadIdx.x;
    if (e >= ET) return;
    const int d = (e < E) ? dst[e] : (e - E);
    atomicAdd(&deg[d], 1);
}

__global__ __launch_bounds__(256) void scan_block(const int* __restrict__ deg,
                                                  int* __restrict__ row_ptr,
                                                  int* __restrict__ partials, int N) {
    __shared__ int sd[256];
    const int tid = threadIdx.x;
    const int base = blockIdx.x * 1024 + tid * 4;
    int v0 = (base + 0 < N) ? deg[base + 0] : 0;
    int v1 = (base + 1 < N) ? deg[base + 1] : 0;
    int v2 = (base + 2 < N) ? deg[base + 2] : 0;
    int v3 = (base + 3 < N) ? deg[base + 3] : 0;
    const int tsum = v0 + v1 + v2 + v3;
    sd[tid] = tsum;
    __syncthreads();
    int run = tsum;
    for (int off = 1; off < 256; off <<= 1) {
        int t = 0;
        if (tid >= off) t = sd[tid - off];
        __syncthreads();
        run += t;
        sd[tid] = run;
        __syncthreads();
    }
    const int excl = run - tsum;
    int s0 = excl + v0, s1 = s0 + v1, s2 = s1 + v2, s3 = s2 + v3;
    if (base + 0 < N) row_ptr[base + 1] = s0;
    if (base + 1 < N) row_ptr[base + 2] = s1;
    if (base + 2 < N) row_ptr[base + 3] = s2;
    if (base + 3 < N) row_ptr[base + 4] = s3;
    if (tid == 255) partials[blockIdx.x] = run;
}

__global__ __launch_bounds__(1024) void scan_partials(int* __restrict__ partials, int nb) {
    __shared__ int sd[1024];
    const int tid = threadIdx.x;
    int v = (tid < nb) ? partials[tid] : 0;
    sd[tid] = v;
    __syncthreads();
    int run = v;
    for (int off = 1; off < 1024; off <<= 1) {
        int t = 0;
        if (tid >= off) t = sd[tid - off];
        __syncthreads();
        run += t;
        sd[tid] = run;
        __syncthreads();
    }
    if (tid < nb) partials[tid] = run - v;  // exclusive
}

__global__ __launch_bounds__(256) void scan_add(int* __restrict__ row_ptr,
                                                const int* __restrict__ partials, int N) {
    const int i = blockIdx.x * 256 + threadIdx.x;
    if (i == 0) row_ptr[0] = 0;
    if (i < N) row_ptr[i + 1] += partials[i >> 10];
}

__global__ void scatter_edges(const int* __restrict__ dst, int E, int ET,
                              const int* __restrict__ row_ptr, int* __restrict__ cursor,
                              int* __restrict__ eids) {
    const int e = blockIdx.x * blockDim.x + threadIdx.x;
    if (e >= ET) return;
    const int d = (e < E) ? dst[e] : (e - E);
    const int pos = atomicAdd(&cursor[d], 1);
    eids[row_ptr[d] + pos] = e;
}

// ---------------------------------------------------------------------------
// GAT aggregation, chunked online-softmax. One block = one dst node.
// ---------------------------------------------------------------------------
__global__ __launch_bounds__(256) void gat_aggregate(
    const float* __restrict__ h, const float* __restrict__ a_src,
    const float* __restrict__ a_dst, const int* __restrict__ row_ptr,
    const int* __restrict__ eids, const int* __restrict__ src_arr, int E,
    const float* __restrict__ bias, float* __restrict__ out) {
    const int n = blockIdx.x;
    const int tid = threadIdx.x;
    const int beg = row_ptr[n];
    const int deg = row_ptr[n + 1] - beg;

    __shared__ int   srcs[CH];
    __shared__ float ev[CH][NH];
    __shared__ float red[32];
    __shared__ float mxs[NH], scl[NH];
    __shared__ float m_run[NH], d_run[NH];

    if (tid < NH) { m_run[tid] = -1e30f; d_run[tid] = 0.f; }

    const int hh = tid & 7;
    const int slot = tid >> 3;
    const int h8 = tid >> 5;
    float acc = 0.f;

    for (int c0 = 0; c0 < deg; c0 += CH) {
        const int chlen = min(CH, deg - c0);
        __syncthreads();

        if (tid < chlen) {
            const int e = eids[beg + c0 + tid];
            const int s = (e < E) ? src_arr[e] : (e - E);
            srcs[tid] = s;
            const float4 as0 = *(const float4*)&a_src[s * NH];
            const float4 as1 = *(const float4*)&a_src[s * NH + 4];
            const float4 ad0 = *(const float4*)&a_dst[n * NH];
            const float4 ad1 = *(const float4*)&a_dst[n * NH + 4];
            float4 w0, w1;
            w0.x = as0.x + ad0.x; w0.y = as0.y + ad0.y;
            w0.z = as0.z + ad0.z; w0.w = as0.w + ad0.w;
            w1.x = as1.x + ad1.x; w1.y = as1.y + ad1.y;
            w1.z = as1.z + ad1.z; w1.w = as1.w + ad1.w;
            w0.x = w0.x > 0.f ? w0.x : NEG_SLOPE * w0.x;
            w0.y = w0.y > 0.f ? w0.y : NEG_SLOPE * w0.y;
            w0.z = w0.z > 0.f ? w0.z : NEG_SLOPE * w0.z;
            w0.w = w0.w > 0.f ? w0.w : NEG_SLOPE * w0.w;
            w1.x = w1.x > 0.f ? w1.x : NEG_SLOPE * w1.x;
            w1.y = w1.y > 0.f ? w1.y : NEG_SLOPE * w1.y;
            w1.z = w1.z > 0.f ? w1.z : NEG_SLOPE * w1.z;
            w1.w = w1.w > 0.f ? w1.w : NEG_SLOPE * w1.w;
            *(float4*)&ev[tid][0] = w0;
            *(float4*)&ev[tid][4] = w1;
        }
        __syncthreads();

        float lmax = -1e30f;
        for (int j = slot; j < chlen; j += 32) lmax = fmaxf(lmax, ev[j][hh]);
        lmax = fmaxf(lmax, __shfl_xor(lmax, 8));
        lmax = fmaxf(lmax, __shfl_xor(lmax, 16));
        lmax = fmaxf(lmax, __shfl_xor(lmax, 32));
        if ((tid & 63) < 8) red[(tid >> 6) * 8 + hh] = lmax;
        __syncthreads();
        if (tid < NH) {
            float mn = fmaxf(fmaxf(red[tid], red[8 + tid]),
                             fmaxf(red[16 + tid], red[24 + tid]));
            const float mo = m_run[tid];
            mn = fmaxf(mo, mn);
            m_run[tid] = mn;
            mxs[tid] = mn;
            scl[tid] = __expf(mo - mn);
        }
        __syncthreads();

        const float mh = mxs[hh];
        float lsum = 0.f;
        for (int j = slot; j < chlen; j += 32) {
            const float p = __expf(ev[j][hh] - mh);
            ev[j][hh] = p;
            lsum += p;
        }
        lsum += __shfl_xor(lsum, 8);
        lsum += __shfl_xor(lsum, 16);
        lsum += __shfl_xor(lsum, 32);
        if ((tid & 63) < 8) red[(tid >> 6) * 8 + hh] = lsum;
        __syncthreads();
        if (tid < NH)
            d_run[tid] = d_run[tid] * scl[tid] +
                         ((red[tid] + red[8 + tid]) + (red[16 + tid] + red[24 + tid]));
        __syncthreads();

        float t0 = 0.f, t1 = 0.f, t2 = 0.f, t3 = 0.f;
        int j = 0;
        for (; j + 4 <= chlen; j += 4) {
            const int s0 = srcs[j], s1 = srcs[j + 1], s2 = srcs[j + 2], s3 = srcs[j + 3];
            const float p0 = ev[j][h8], p1 = ev[j + 1][h8];
            const float p2 = ev[j + 2][h8], p3 = ev[j + 3][h8];
            t0 += p0 * h[(size_t)s0 * HC + tid];
            t1 += p1 * h[(size_t)s1 * HC + tid];
            t2 += p2 * h[(size_t)s2 * HC + tid];
            t3 += p3 * h[(size_t)s3 * HC + tid];
        }
        for (; j < chlen; j++) t0 += ev[j][h8] * h[(size_t)srcs[j] * HC + tid];
        acc = acc * scl[h8] + ((t0 + t1) + (t2 + t3));
    }

    const float invd = 1.f / (d_run[h8] + 1e-16f);
    out[(size_t)n * HC + tid] = fmaxf(acc * invd + bias[tid], 0.f);
}

// ---------------------------------------------------------------------------
// Pooling stage 1: block owns 64 consecutive nodes (batch sorted); per-feature
// partial sums per graph-run, one atomicAdd per (run, feature).
// ---------------------------------------------------------------------------
__global__ __launch_bounds__(256) void pool_partial(const float* __restrict__ h,
                                                    const int* __restrict__ batch, int N,
                                                    float* __restrict__ sums) {
    __shared__ int bs[64];
    const int tid = threadIdx.x;
    const int base = blockIdx.x * 64;
    const int cnt = min(64, N - base);
    if (tid < 64 && tid < cnt) bs[tid] = batch[base + tid];
    __syncthreads();

    float acc = 0.f;
    int cur = bs[0];
    for (int i = 0; i < cnt; i++) {
        const int g = bs[i];
        if (g != cur) {
            atomicAdd(&sums[(size_t)cur * HC + tid], acc);
            acc = 0.f;
            cur = g;
        }
        acc += h[(size_t)(base + i) * HC + tid];
    }
    atomicAdd(&sums[(size_t)cur * HC + tid], acc);
}

// ---------------------------------------------------------------------------
// Pooling stage 2: divide by graph node-count (binary search on sorted batch).
// ---------------------------------------------------------------------------
__global__ __launch_bounds__(256) void pool_div(float* __restrict__ sums,
                                                const int* __restrict__ batch, int N) {
    const int g = blockIdx.x;
    const int tid = threadIdx.x;
    int lo = 0, hi = N;
    while (lo < hi) {
        const int mid = (lo + hi) >> 1;
        if (batch[mid] < g) lo = mid + 1; else hi = mid;
    }
    const int start = lo;
    hi = N;
    while (lo < hi) {
        const int mid = (lo + hi) >> 1;
        if (batch[mid] < g + 1) lo = mid + 1; else hi = mid;
    }
    const float inv = 1.f / fmaxf((float)(lo - start), 1.0f);
    sums[(size_t)g * HC + tid] *= inv;
}

// ---------------------------------------------------------------------------
// MLP head
// ---------------------------------------------------------------------------
__global__ __launch_bounds__(128) void mlp_head(const float* __restrict__ pooled,
                                                const float* __restrict__ w1,
                                                const float* __restrict__ b1,
                                                const float* __restrict__ w2,
                                                const float* __restrict__ b2,
                                                float* __restrict__ out) {
    const int g = blockIdx.x;
    const int tid = threadIdx.x;
    __shared__ float p[HC];
    p[tid] = pooled[g * HC + tid];
    p[tid + 128] = pooled[g * HC + tid + 128];
    __syncthreads();
    float z = b1[tid];
#pragma unroll 8
    for (int k = 0; k < HC; k++) z += p[k] * w1[k * 128 + tid];
    z = fmaxf(z, 0.f);
    float t = z * w2[tid];
#pragma unroll
    for (int m = 32; m >= 1; m >>= 1) t += __shfl_xor(t, m);
    __shared__ float ws2[2];
    if ((tid & 63) == 0) ws2[tid >> 6] = t;
    __syncthreads();
    if (tid == 0) out[g] = ws2[0] + ws2[1] + b2[0];
}

// ---------------------------------------------------------------------------
// Host-side launcher
// ---------------------------------------------------------------------------
extern "C" void kernel_launch(void* const* d_in, const int* in_sizes, int n_in,
                              void* d_out, int out_size, void* d_ws, size_t ws_size,
                              hipStream_t stream) {
    const float* x      = (const float*)d_in[0];
    const int*   ei     = (const int*)d_in[1];
    const int*   batch  = (const int*)d_in[2];
    const float* W1     = (const float*)d_in[3];
    const float* as1    = (const float*)d_in[4];
    const float* ad1    = (const float*)d_in[5];
    const float* b1     = (const float*)d_in[6];
    const float* W2     = (const float*)d_in[7];
    const float* as2    = (const float*)d_in[8];
    const float* ad2    = (const float*)d_in[9];
    const float* b2     = (const float*)d_in[10];
    const float* lin1w  = (const float*)d_in[11];
    const float* lin1b  = (const float*)d_in[12];
    const float* lin2w  = (const float*)d_in[13];
    const float* lin2b  = (const float*)d_in[14];

    const int N   = in_sizes[2];       // 50000
    const int E   = in_sizes[1] / 2;   // 800000
    const int ET  = E + N;
    const int Fin = in_sizes[0] / N;   // 1280
    const int NG  = 64;

    const int nRB    = (N + 63) / 64;
    const int halfRB = (nRB + 1) / 2;
    const int rowsHalf = halfRB * 64;
    const int KT1 = Fin / 32;
    const int KT2 = HC / 32;
    const int nScanBlk = (N + 1023) / 1024;

    const int* src_arr = ei;
    const int* dst_arr = ei + E;

    char* ws = (char*)d_ws;
    size_t off = 0;
    auto alloc = [&](size_t bytes) {
        void* p = ws + off;
        off += (bytes + 255) & ~(size_t)255;
        return p;
    };
    float* h_gemm  = (float*)alloc((size_t)N * HC * sizeof(float));
    float* h_agg   = (float*)alloc((size_t)N * HC * sizeof(float));
    float* a_src   = (float*)alloc((size_t)N * NH * sizeof(float));
    float* a_dst   = (float*)alloc((size_t)N * NH * sizeof(float));
    int*   deg     = (int*)alloc((size_t)N * sizeof(int));
    int*   cursor  = (int*)alloc((size_t)N * sizeof(int));
    int*   row_ptr = (int*)alloc((size_t)(N + 1) * sizeof(int));
    int*   partials= (int*)alloc((size_t)1024 * sizeof(int));
    int*   eids    = (int*)alloc((size_t)ET * sizeof(int));
    float* pooled  = (float*)alloc((size_t)NG * HC * sizeof(float));
    size_t aElems = (size_t)rowsHalf * Fin;
    const size_t a2Elems = (size_t)nRB * 64 * HC;
    if (a2Elems > aElems) aElems = a2Elems;
    u16* Ah = (u16*)alloc(aElems * sizeof(u16));
    u16* Al = (u16*)alloc(aElems * sizeof(u16));
    u16* Bh = (u16*)alloc((size_t)Fin * HC * sizeof(u16));
    u16* Bl = (u16*)alloc((size_t)Fin * HC * sizeof(u16));
    (void)ws_size; (void)n_in; (void)out_size;

    // ---- CSR build ----
    hipMemsetAsync(deg, 0, (size_t)N * sizeof(int), stream);
    hipMemsetAsync(cursor, 0, (size_t)N * sizeof(int), stream);
    {
        const int blocks = (ET + 255) / 256;
        count_deg<<<blocks, 256, 0, stream>>>(dst_arr, E, ET, deg);
        scan_block<<<nScanBlk, 256, 0, stream>>>(deg, row_ptr, partials, N);
        scan_partials<<<1, 1024, 0, stream>>>(partials, nScanBlk);
        scan_add<<<(N + 255) / 256, 256, 0, stream>>>(row_ptr, partials, N);
        scatter_edges<<<blocks, 256, 0, stream>>>(dst_arr, E, ET, row_ptr, cursor, eids);
    }

    // ---- Layer 1 ----
    pack_b_split<<<KT1 * 4, 256, 0, stream>>>(W1, Fin, Bh, Bl);
    for (int half = 0; half < 2; half++) {
        const int rb = (half == 0) ? halfRB : (nRB - halfRB);
        pack_a_split<<<dim3(rb, KT1), 256, 0, stream>>>(x, N, Fin, half * rowsHalf, Ah, Al);
        const int mloc = N - half * rowsHalf < rowsHalf ? N - half * rowsHalf : rowsHalf;
        gemm_mfma_split<<<rb, 256, 0, stream>>>(Ah, Al, Bh, Bl,
                                                h_gemm + (size_t)half * rowsHalf * HC,
                                                mloc, KT1);
    }
    attn_coef<<<N, 256, 0, stream>>>(h_gemm, as1, ad1, a_src, a_dst);
    gat_aggregate<<<N, 256, 0, stream>>>(h_gemm, a_src, a_dst, row_ptr, eids, src_arr, E,
                                         b1, h_agg);

    // ---- Layer 2 ----
    pack_b_split<<<KT2 * 4, 256, 0, stream>>>(W2, HC, Bh, Bl);
    pack_a_split<<<dim3(nRB, KT2), 256, 0, stream>>>(h_agg, N, HC, 0, Ah, Al);
    gemm_mfma_split<<<nRB, 256, 0, stream>>>(Ah, Al, Bh, Bl, h_gemm, N, KT2);
    attn_coef<<<N, 256, 0, stream>>>(h_gemm, as2, ad2, a_src, a_dst);
    gat_aggregate<<<N, 256, 0, stream>>>(h_gemm, a_src, a_dst, row_ptr, eids, src_arr, E,
                                         b2, h_agg);

    // ---- Pool + MLP head ----
    hipMemsetAsync(pooled, 0, (size_t)NG * HC * sizeof(float), stream);
    pool_partial<<<(N + 63) / 64, 256, 0, stream>>>(h_agg, batch, N, pooled);
    pool_div<<<NG, 256, 0, stream>>>(pooled, batch, N);
    mlp_head<<<NG, 128, 0, stream>>>(pooled, lin1w, lin1b, lin2w, lin2b, (float*)d_out);
}

// Round 5
// 658.516 us; speedup vs baseline: 2.5771x; 1.1290x over previous
//
#include <hip/hip_runtime.h>
#include <hip/hip_bf16.h>
#include <math.h>

#define HC 256
#define NH 8
#define NEG_SLOPE 0.2f
#define CHW 64   // edges per chunk per wave (aggregation)

typedef unsigned short u16;
typedef __attribute__((ext_vector_type(8))) short bf16x8;
typedef __attribute__((ext_vector_type(4))) float f32x4;

__device__ __forceinline__ u16 f2bf(float f) {
    unsigned int u = __float_as_uint(f);
    u += 0x7FFFu + ((u >> 16) & 1u);
    return (u16)(u >> 16);
}
__device__ __forceinline__ float bf2f(u16 s) {
    return __uint_as_float(((unsigned int)s) << 16);
}

// ---------------------------------------------------------------------------
// pack B (fp32 [K x 256]) -> hi/lo, fragment-major:
// chunk g = kt*1024 + f*64 + lane; col = f*16 + (lane&15); k = kt*32+(lane>>4)*8+e
// ---------------------------------------------------------------------------
__global__ __launch_bounds__(256) void pack_b_split(const float* __restrict__ B, int K,
                                                    u16* __restrict__ Bh,
                                                    u16* __restrict__ Bl) {
    const int g = blockIdx.x * 256 + threadIdx.x;
    const int lane = g & 63;
    const int f = (g >> 6) & 15;
    const int kt = g >> 10;
    const int col = f * 16 + (lane & 15);
    const int k0 = kt * 32 + (lane >> 4) * 8;
    bf16x8 hv, lv;
#pragma unroll
    for (int e = 0; e < 8; e++) {
        const float v = B[(size_t)(k0 + e) * HC + col];
        const u16 h = f2bf(v);
        hv[e] = (short)h;
        lv[e] = (short)f2bf(v - bf2f(h));
    }
    const size_t off = (size_t)g * 8;
    *(bf16x8*)(Bh + off) = hv;
    *(bf16x8*)(Bl + off) = lv;
}

// ---------------------------------------------------------------------------
// Fused split-precision MFMA GEMM: C[64*blk .. +64, 256] = A(fp32) @ B(packed)
// A staged fp32 into padded LDS, converted in-register to hi/lo bf16 frags.
// 256 threads = 4 waves; wave w owns cols [w*64, w*64+64); 4x4 16x16x32 frags.
// C = Ah*Bh + Al*Bh + Ah*Bl  (~fp32 accuracy).
// ---------------------------------------------------------------------------
__global__ __launch_bounds__(256) void gemm_fused_split(
    const float* __restrict__ A,
    const u16* __restrict__ Bh, const u16* __restrict__ Bl,
    float* __restrict__ C, int M, int K) {
    __shared__ float tile[64][36];   // +4 pad: 144B row stride (16B aligned)
    const int tid = threadIdx.x;
    const int wid = tid >> 6;
    const int lane = tid & 63;
    const int rowblk = blockIdx.x;
    const int KT = K >> 5;

    f32x4 acc[4][4];
#pragma unroll
    for (int i = 0; i < 4; i++)
#pragma unroll
        for (int j = 0; j < 4; j++) acc[i][j] = (f32x4)0.f;

    // A staging map: thread loads row srow, k [skq, skq+8)
    const int srow = tid >> 2;
    const int skq = (tid & 3) * 8;
    const int grow = rowblk * 64 + srow;
    const float* aptr = (grow < M) ? (A + (size_t)grow * K) : nullptr;

    for (int kt = 0; kt < KT; kt++) {
        float4 v0 = make_float4(0.f, 0.f, 0.f, 0.f), v1 = v0;
        if (aptr) {
            v0 = *(const float4*)(aptr + kt * 32 + skq);
            v1 = *(const float4*)(aptr + kt * 32 + skq + 4);
        }
        // B fragments direct to VGPR (L2-resident); wave w takes frags w*4+j
        const u16* bH = Bh + ((size_t)kt * 16 + wid * 4) * 512;
        const u16* bL = Bl + ((size_t)kt * 16 + wid * 4) * 512;
        bf16x8 bh[4], bl[4];
#pragma unroll
        for (int j = 0; j < 4; j++) {
            bh[j] = *(const bf16x8*)(bH + j * 512 + lane * 8);
            bl[j] = *(const bf16x8*)(bL + j * 512 + lane * 8);
        }
        __syncthreads();   // previous iteration's tile reads complete
        *(float4*)&tile[srow][skq] = v0;
        *(float4*)&tile[srow][skq + 4] = v1;
        __syncthreads();   // tile ready

        bf16x8 ah[4], al[4];
#pragma unroll
        for (int i = 0; i < 4; i++) {
            const int row = i * 16 + (lane & 15);
            const float* tp = &tile[row][(lane >> 4) * 8];
            const f32x4 f0 = *(const f32x4*)tp;
            const f32x4 f1 = *(const f32x4*)(tp + 4);
#pragma unroll
            for (int e = 0; e < 4; e++) {
                const u16 h0 = f2bf(f0[e]);
                ah[i][e] = (short)h0;
                al[i][e] = (short)f2bf(f0[e] - bf2f(h0));
                const u16 h1 = f2bf(f1[e]);
                ah[i][4 + e] = (short)h1;
                al[i][4 + e] = (short)f2bf(f1[e] - bf2f(h1));
            }
        }
#pragma unroll
        for (int i = 0; i < 4; i++)
#pragma unroll
            for (int j = 0; j < 4; j++) {
                acc[i][j] = __builtin_amdgcn_mfma_f32_16x16x32_bf16(ah[i], bh[j], acc[i][j], 0, 0, 0);
                acc[i][j] = __builtin_amdgcn_mfma_f32_16x16x32_bf16(al[i], bh[j], acc[i][j], 0, 0, 0);
                acc[i][j] = __builtin_amdgcn_mfma_f32_16x16x32_bf16(ah[i], bl[j], acc[i][j], 0, 0, 0);
            }
    }

    // epilogue: C/D layout col = lane&15, row = (lane>>4)*4 + r
    const int r0 = rowblk * 64;
    const int colb = wid * 64 + (lane & 15);
#pragma unroll
    for (int i = 0; i < 4; i++) {
#pragma unroll
        for (int r = 0; r < 4; r++) {
            const int row = r0 + i * 16 + (lane >> 4) * 4 + r;
            if (row < M) {
#pragma unroll
                for (int j = 0; j < 4; j++)
                    C[(size_t)row * HC + colb + j * 16] = acc[i][j][r];
            }
        }
    }
}

// ---------------------------------------------------------------------------
// Per-node attention coefficients
// ---------------------------------------------------------------------------
__global__ __launch_bounds__(256) void attn_coef(const float* __restrict__ h,
                                                 const float* __restrict__ att_s,
                                                 const float* __restrict__ att_d,
                                                 float* __restrict__ a_src,
                                                 float* __restrict__ a_dst) {
    const int n = blockIdx.x;
    const int tid = threadIdx.x;
    const float hv = h[(size_t)n * HC + tid];
    float p = hv * att_s[tid];
    float q = hv * att_d[tid];
#pragma unroll
    for (int m = 16; m >= 1; m >>= 1) {
        p += __shfl_xor(p, m);
        q += __shfl_xor(q, m);
    }
    if ((tid & 31) == 0) {
        a_src[n * NH + (tid >> 5)] = p;
        a_dst[n * NH + (tid >> 5)] = q;
    }
}

// ---------------------------------------------------------------------------
// CSR build: count, two-level scan, scatter
// ---------------------------------------------------------------------------
__global__ void count_deg(const int* __restrict__ dst, int E, int ET, int* __restrict__ deg) {
    const int e = blockIdx.x * blockDim.x + threadIdx.x;
    if (e >= ET) return;
    const int d = (e < E) ? dst[e] : (e - E);
    atomicAdd(&deg[d], 1);
}

__global__ __launch_bounds__(256) void scan_block(const int* __restrict__ deg,
                                                  int* __restrict__ row_ptr,
                                                  int* __restrict__ partials, int N) {
    __shared__ int sd[256];
    const int tid = threadIdx.x;
    const int base = blockIdx.x * 1024 + tid * 4;
    int v0 = (base + 0 < N) ? deg[base + 0] : 0;
    int v1 = (base + 1 < N) ? deg[base + 1] : 0;
    int v2 = (base + 2 < N) ? deg[base + 2] : 0;
    int v3 = (base + 3 < N) ? deg[base + 3] : 0;
    const int tsum = v0 + v1 + v2 + v3;
    sd[tid] = tsum;
    __syncthreads();
    int run = tsum;
    for (int off = 1; off < 256; off <<= 1) {
        int t = 0;
        if (tid >= off) t = sd[tid - off];
        __syncthreads();
        run += t;
        sd[tid] = run;
        __syncthreads();
    }
    const int excl = run - tsum;
    int s0 = excl + v0, s1 = s0 + v1, s2 = s1 + v2, s3 = s2 + v3;
    if (base + 0 < N) row_ptr[base + 1] = s0;
    if (base + 1 < N) row_ptr[base + 2] = s1;
    if (base + 2 < N) row_ptr[base + 3] = s2;
    if (base + 3 < N) row_ptr[base + 4] = s3;
    if (tid == 255) partials[blockIdx.x] = run;
}

__global__ __launch_bounds__(1024) void scan_partials(int* __restrict__ partials, int nb) {
    __shared__ int sd[1024];
    const int tid = threadIdx.x;
    int v = (tid < nb) ? partials[tid] : 0;
    sd[tid] = v;
    __syncthreads();
    int run = v;
    for (int off = 1; off < 1024; off <<= 1) {
        int t = 0;
        if (tid >= off) t = sd[tid - off];
        __syncthreads();
        run += t;
        sd[tid] = run;
        __syncthreads();
    }
    if (tid < nb) partials[tid] = run - v;  // exclusive
}

__global__ __launch_bounds__(256) void scan_add(int* __restrict__ row_ptr,
                                                const int* __restrict__ partials, int N) {
    const int i = blockIdx.x * 256 + threadIdx.x;
    if (i == 0) row_ptr[0] = 0;
    if (i < N) row_ptr[i + 1] += partials[i >> 10];
}

__global__ void scatter_edges(const int* __restrict__ dst, int E, int ET,
                              const int* __restrict__ row_ptr, int* __restrict__ cursor,
                              int* __restrict__ eids) {
    const int e = blockIdx.x * blockDim.x + threadIdx.x;
    if (e >= ET) return;
    const int d = (e < E) ? dst[e] : (e - E);
    const int pos = atomicAdd(&cursor[d], 1);
    eids[row_ptr[d] + pos] = e;
}

// ---------------------------------------------------------------------------
// GAT aggregation, one WAVE per dst node (wave-synchronous, no block barriers).
// Softmax lanes: (edge-slot jj = lane>>3, head hh = lane&7), 8 edges/pass.
// Gather: per edge, 64 lanes x f32x4 = exactly the 1KB feature row.
// Feature ownership in phase 4: lane owns f = lane*4..lane*4+3, head = lane>>3.
// ---------------------------------------------------------------------------
__global__ __launch_bounds__(256) void gat_aggregate_wave(
    const float* __restrict__ h, const float* __restrict__ a_src,
    const float* __restrict__ a_dst, const int* __restrict__ row_ptr,
    const int* __restrict__ eids, const int* __restrict__ src_arr, int E,
    const float* __restrict__ bias, float* __restrict__ out, int N) {
    __shared__ int   s_src[4][CHW];
    __shared__ float s_ev[4][CHW][NH];

    const int tid = threadIdx.x;
    const int wv = tid >> 6;
    const int lane = tid & 63;
    const int n = blockIdx.x * 4 + wv;
    if (n >= N) return;

    const int beg = row_ptr[n];
    const int deg = row_ptr[n + 1] - beg;
    const int jj = lane >> 3;   // edge slot 0..7
    const int hh = lane & 7;    // head for softmax lanes
    const int g4 = lane >> 3;   // head for gather features (lane*4..+3 all in head lane>>3)

    const float adh = a_dst[n * NH + hh];
    float m_run = -1e30f, d_run = 0.f;
    f32x4 acc = (f32x4)0.f;

    for (int c0 = 0; c0 < deg; c0 += CHW) {
        const int chlen = min(CHW, deg - c0);

        // ---- phase 1: e-values into LDS, track chunk max ----
        float lmax = -1e30f;
        for (int p = 0; p < chlen; p += 8) {
            const int j = p + jj;
            if (j < chlen) {
                const int e = eids[beg + c0 + j];
                const int s = (e < E) ? src_arr[e] : (e - E);
                if (hh == 0) s_src[wv][j] = s;
                float v = a_src[s * NH + hh] + adh;
                v = (v > 0.f) ? v : NEG_SLOPE * v;
                s_ev[wv][j][hh] = v;
                lmax = fmaxf(lmax, v);
            }
        }
        // reduce max over the 8 edge-slots (lanes hh, hh+8, ..., hh+56)
        lmax = fmaxf(lmax, __shfl_xor(lmax, 8));
        lmax = fmaxf(lmax, __shfl_xor(lmax, 16));
        lmax = fmaxf(lmax, __shfl_xor(lmax, 32));
        const float mo = m_run;
        const float mn = fmaxf(mo, lmax);
        const float scl = __expf(mo - mn);   // exp(-inf - ...) -> 0 first time
        m_run = mn;

        // ---- phase 2: exp in LDS (own entries), chunk sum ----
        float lsum = 0.f;
        for (int p = 0; p < chlen; p += 8) {
            const int j = p + jj;
            if (j < chlen) {
                const float pv = __expf(s_ev[wv][j][hh] - mn);
                s_ev[wv][j][hh] = pv;
                lsum += pv;
            }
        }
        lsum += __shfl_xor(lsum, 8);
        lsum += __shfl_xor(lsum, 16);
        lsum += __shfl_xor(lsum, 32);
        d_run = d_run * scl + lsum;

        // LDS writes (s_ev exp, s_src) must land before cross-lane reads
        __asm__ volatile("s_waitcnt lgkmcnt(0)" ::: "memory");

        // ---- phase 3: gather ----
        const float scl4 = __shfl(scl, g4);   // lane g4 holds head-g4 value
        f32x4 t = (f32x4)0.f;
        int j = 0;
        for (; j + 2 <= chlen; j += 2) {
            const int s0 = s_src[wv][j];
            const int s1 = s_src[wv][j + 1];
            const float p0 = s_ev[wv][j][g4];
            const float p1 = s_ev[wv][j + 1][g4];
            const f32x4 h0 = *(const f32x4*)&h[(size_t)s0 * HC + lane * 4];
            const f32x4 h1 = *(const f32x4*)&h[(size_t)s1 * HC + lane * 4];
#pragma unroll
            for (int q = 0; q < 4; q++) t[q] += p0 * h0[q] + p1 * h1[q];
        }
        if (j < chlen) {
            const int s0 = s_src[wv][j];
            const float p0 = s_ev[wv][j][g4];
            const f32x4 h0 = *(const f32x4*)&h[(size_t)s0 * HC + lane * 4];
#pragma unroll
            for (int q = 0; q < 4; q++) t[q] += p0 * h0[q];
        }
#pragma unroll
        for (int q = 0; q < 4; q++) acc[q] = acc[q] * scl4 + t[q];
    }

    const float invd = 1.f / (__shfl(d_run, g4) + 1e-16f);
    const f32x4 bv = *(const f32x4*)&bias[lane * 4];
    f32x4 o;
#pragma unroll
    for (int q = 0; q < 4; q++) o[q] = fmaxf(acc[q] * invd + bv[q], 0.f);
    *(f32x4*)&out[(size_t)n * HC + lane * 4] = o;
}

// ---------------------------------------------------------------------------
// Pooling stage 1: block owns 64 consecutive nodes (batch sorted); per-feature
// partial sums per graph-run, one atomicAdd per (run, feature).
// ---------------------------------------------------------------------------
__global__ __launch_bounds__(256) void pool_partial(const float* __restrict__ h,
                                                    const int* __restrict__ batch, int N,
                                                    float* __restrict__ sums) {
    __shared__ int bs[64];
    const int tid = threadIdx.x;
    const int base = blockIdx.x * 64;
    const int cnt = min(64, N - base);
    if (tid < 64 && tid < cnt) bs[tid] = batch[base + tid];
    __syncthreads();

    float acc = 0.f;
    int cur = bs[0];
    for (int i = 0; i < cnt; i++) {
        const int g = bs[i];
        if (g != cur) {
            atomicAdd(&sums[(size_t)cur * HC + tid], acc);
            acc = 0.f;
            cur = g;
        }
        acc += h[(size_t)(base + i) * HC + tid];
    }
    atomicAdd(&sums[(size_t)cur * HC + tid], acc);
}

__global__ __launch_bounds__(256) void pool_div(float* __restrict__ sums,
                                                const int* __restrict__ batch, int N) {
    const int g = blockIdx.x;
    const int tid = threadIdx.x;
    int lo = 0, hi = N;
    while (lo < hi) {
        const int mid = (lo + hi) >> 1;
        if (batch[mid] < g) lo = mid + 1; else hi = mid;
    }
    const int start = lo;
    hi = N;
    while (lo < hi) {
        const int mid = (lo + hi) >> 1;
        if (batch[mid] < g + 1) lo = mid + 1; else hi = mid;
    }
    const float inv = 1.f / fmaxf((float)(lo - start), 1.0f);
    sums[(size_t)g * HC + tid] *= inv;
}

// ---------------------------------------------------------------------------
// MLP head
// ---------------------------------------------------------------------------
__global__ __launch_bounds__(128) void mlp_head(const float* __restrict__ pooled,
                                                const float* __restrict__ w1,
                                                const float* __restrict__ b1,
                                                const float* __restrict__ w2,
                                                const float* __restrict__ b2,
                                                float* __restrict__ out) {
    const int g = blockIdx.x;
    const int tid = threadIdx.x;
    __shared__ float p[HC];
    p[tid] = pooled[g * HC + tid];
    p[tid + 128] = pooled[g * HC + tid + 128];
    __syncthreads();
    float z = b1[tid];
#pragma unroll 8
    for (int k = 0; k < HC; k++) z += p[k] * w1[k * 128 + tid];
    z = fmaxf(z, 0.f);
    float t = z * w2[tid];
#pragma unroll
    for (int m = 32; m >= 1; m >>= 1) t += __shfl_xor(t, m);
    __shared__ float ws2[2];
    if ((tid & 63) == 0) ws2[tid >> 6] = t;
    __syncthreads();
    if (tid == 0) out[g] = ws2[0] + ws2[1] + b2[0];
}

// ---------------------------------------------------------------------------
// Host-side launcher
// ---------------------------------------------------------------------------
extern "C" void kernel_launch(void* const* d_in, const int* in_sizes, int n_in,
                              void* d_out, int out_size, void* d_ws, size_t ws_size,
                              hipStream_t stream) {
    const float* x      = (const float*)d_in[0];
    const int*   ei     = (const int*)d_in[1];
    const int*   batch  = (const int*)d_in[2];
    const float* W1     = (const float*)d_in[3];
    const float* as1    = (const float*)d_in[4];
    const float* ad1    = (const float*)d_in[5];
    const float* b1     = (const float*)d_in[6];
    const float* W2     = (const float*)d_in[7];
    const float* as2    = (const float*)d_in[8];
    const float* ad2    = (const float*)d_in[9];
    const float* b2     = (const float*)d_in[10];
    const float* lin1w  = (const float*)d_in[11];
    const float* lin1b  = (const float*)d_in[12];
    const float* lin2w  = (const float*)d_in[13];
    const float* lin2b  = (const float*)d_in[14];

    const int N   = in_sizes[2];       // 50000
    const int E   = in_sizes[1] / 2;   // 800000
    const int ET  = E + N;
    const int Fin = in_sizes[0] / N;   // 1280
    const int NG  = 64;

    const int nRB = (N + 63) / 64;
    const int nScanBlk = (N + 1023) / 1024;

    const int* src_arr = ei;
    const int* dst_arr = ei + E;

    char* ws = (char*)d_ws;
    size_t off = 0;
    auto alloc = [&](size_t bytes) {
        void* p = ws + off;
        off += (bytes + 255) & ~(size_t)255;
        return p;
    };
    float* h_gemm  = (float*)alloc((size_t)N * HC * sizeof(float));
    float* h_agg   = (float*)alloc((size_t)N * HC * sizeof(float));
    float* a_src   = (float*)alloc((size_t)N * NH * sizeof(float));
    float* a_dst   = (float*)alloc((size_t)N * NH * sizeof(float));
    int*   deg     = (int*)alloc((size_t)N * sizeof(int));
    int*   cursor  = (int*)alloc((size_t)N * sizeof(int));
    int*   row_ptr = (int*)alloc((size_t)(N + 1) * sizeof(int));
    int*   partials= (int*)alloc((size_t)1024 * sizeof(int));
    int*   eids    = (int*)alloc((size_t)ET * sizeof(int));
    float* pooled  = (float*)alloc((size_t)NG * HC * sizeof(float));
    u16* Bh = (u16*)alloc((size_t)Fin * HC * sizeof(u16));
    u16* Bl = (u16*)alloc((size_t)Fin * HC * sizeof(u16));
    (void)ws_size; (void)n_in; (void)out_size;

    // ---- CSR build ----
    hipMemsetAsync(deg, 0, (size_t)N * sizeof(int), stream);
    hipMemsetAsync(cursor, 0, (size_t)N * sizeof(int), stream);
    {
        const int blocks = (ET + 255) / 256;
        count_deg<<<blocks, 256, 0, stream>>>(dst_arr, E, ET, deg);
        scan_block<<<nScanBlk, 256, 0, stream>>>(deg, row_ptr, partials, N);
        scan_partials<<<1, 1024, 0, stream>>>(partials, nScanBlk);
        scan_add<<<(N + 255) / 256, 256, 0, stream>>>(row_ptr, partials, N);
        scatter_edges<<<blocks, 256, 0, stream>>>(dst_arr, E, ET, row_ptr, cursor, eids);
    }

    const int aggBlocks = (N + 3) / 4;

    // ---- Layer 1 ----
    pack_b_split<<<(Fin / 32) * 4, 256, 0, stream>>>(W1, Fin, Bh, Bl);
    gemm_fused_split<<<nRB, 256, 0, stream>>>(x, Bh, Bl, h_gemm, N, Fin);
    attn_coef<<<N, 256, 0, stream>>>(h_gemm, as1, ad1, a_src, a_dst);
    gat_aggregate_wave<<<aggBlocks, 256, 0, stream>>>(h_gemm, a_src, a_dst, row_ptr,
                                                      eids, src_arr, E, b1, h_agg, N);

    // ---- Layer 2 ----
    pack_b_split<<<(HC / 32) * 4, 256, 0, stream>>>(W2, HC, Bh, Bl);
    gemm_fused_split<<<nRB, 256, 0, stream>>>(h_agg, Bh, Bl, h_gemm, N, HC);
    attn_coef<<<N, 256, 0, stream>>>(h_gemm, as2, ad2, a_src, a_dst);
    gat_aggregate_wave<<<aggBlocks, 256, 0, stream>>>(h_gemm, a_src, a_dst, row_ptr,
                                                      eids, src_arr, E, b2, h_agg, N);

    // ---- Pool + MLP head ----
    hipMemsetAsync(pooled, 0, (size_t)NG * HC * sizeof(float), stream);
    pool_partial<<<(N + 63) / 64, 256, 0, stream>>>(h_agg, batch, N, pooled);
    pool_div<<<NG, 256, 0, stream>>>(pooled, batch, N);
    mlp_head<<<NG, 128, 0, stream>>>(pooled, lin1w, lin1b, lin2w, lin2b, (float*)d_out);
}

// Round 6
// 641.585 us; speedup vs baseline: 2.6451x; 1.0264x over previous
//
#include <hip/hip_runtime.h>
#include <hip/hip_bf16.h>
#include <math.h>

#define HC 256
#define NH 8
#define NEG_SLOPE 0.2f
#define CHW 64   // edges per chunk per wave (aggregation)

typedef unsigned short u16;
typedef __attribute__((ext_vector_type(8))) short bf16x8;
typedef __attribute__((ext_vector_type(4))) float f32x4;

__device__ __forceinline__ u16 f2bf(float f) {
    unsigned int u = __float_as_uint(f);
    u += 0x7FFFu + ((u >> 16) & 1u);
    return (u16)(u >> 16);
}
__device__ __forceinline__ float bf2f(u16 s) {
    return __uint_as_float(((unsigned int)s) << 16);
}

// ---------------------------------------------------------------------------
// pack B (fp32 [K x 256]) -> hi/lo, fragment-major:
// chunk g = kt*1024 + f*64 + lane; col = f*16 + (lane&15); k = kt*32+(lane>>4)*8+e
// ---------------------------------------------------------------------------
__global__ __launch_bounds__(256) void pack_b_split(const float* __restrict__ B, int K,
                                                    u16* __restrict__ Bh,
                                                    u16* __restrict__ Bl) {
    const int g = blockIdx.x * 256 + threadIdx.x;
    const int lane = g & 63;
    const int f = (g >> 6) & 15;
    const int kt = g >> 10;
    const int col = f * 16 + (lane & 15);
    const int k0 = kt * 32 + (lane >> 4) * 8;
    bf16x8 hv, lv;
#pragma unroll
    for (int e = 0; e < 8; e++) {
        const float v = B[(size_t)(k0 + e) * HC + col];
        const u16 h = f2bf(v);
        hv[e] = (short)h;
        lv[e] = (short)f2bf(v - bf2f(h));
    }
    const size_t off = (size_t)g * 8;
    *(bf16x8*)(Bh + off) = hv;
    *(bf16x8*)(Bl + off) = lv;
}

// ---------------------------------------------------------------------------
// Fused split-precision MFMA GEMM: C[64*blk .. +64, 256] = A(fp32) @ B(packed)
// Staging map: thread tid stages frag f=tid>>6, frag-lane l=tid&63
//   (row = f*16 + (l&15), k-chunk = (l>>4)*8) -> convert ONCE per block,
//   ds_write_b128 fragment-major (linear, conflict-free). Double-buffered LDS,
//   one barrier per k-tile; next A tile prefetched into registers.
// 256 threads = 4 waves; wave w owns cols [w*64, w*64+64); 4x4 16x16x32 frags.
// C = Ah*Bh + Al*Bh + Ah*Bl  (~fp32 accuracy).
// ---------------------------------------------------------------------------
__global__ __launch_bounds__(256) void gemm_fused_split(
    const float* __restrict__ A,
    const u16* __restrict__ Bh, const u16* __restrict__ Bl,
    float* __restrict__ C, int M, int K) {
    __shared__ u16 ldsA[2][4096];   // [buf][hi:0..2048 | lo:2048..4096]
    const int tid = threadIdx.x;
    const int wid = tid >> 6;
    const int lane = tid & 63;
    const int rowblk = blockIdx.x;
    const int KT = K >> 5;

    f32x4 acc[4][4];
#pragma unroll
    for (int i = 0; i < 4; i++)
#pragma unroll
        for (int j = 0; j < 4; j++) acc[i][j] = (f32x4)0.f;

    // staging: this thread owns frag f=wid, lane=tid&63
    const int srow = wid * 16 + (tid & 15);          // row in tile
    const int skq = ((tid >> 4) & 3) * 8;            // k offset in tile
    const int grow = rowblk * 64 + srow;
    const float* aptr = (grow < M) ? (A + (size_t)grow * K + skq) : nullptr;
    u16* myWr = &ldsA[0][wid * 512 + lane * 8];      // buf 0 write slot (u16 units)

    float4 va0 = make_float4(0.f, 0.f, 0.f, 0.f), va1 = va0;
    if (aptr) {
        va0 = *(const float4*)(aptr);
        va1 = *(const float4*)(aptr + 4);
    }
    // convert tile 0 into buf 0
    {
        float vv[8] = {va0.x, va0.y, va0.z, va0.w, va1.x, va1.y, va1.z, va1.w};
        bf16x8 hv, lv;
#pragma unroll
        for (int e = 0; e < 8; e++) {
            const u16 h = f2bf(vv[e]);
            hv[e] = (short)h;
            lv[e] = (short)f2bf(vv[e] - bf2f(h));
        }
        *(bf16x8*)myWr = hv;
        *(bf16x8*)(myWr + 2048) = lv;
    }
    if (aptr && KT > 1) {
        va0 = *(const float4*)(aptr + 32);
        va1 = *(const float4*)(aptr + 36);
    }
    __syncthreads();

    int cur = 0;
    for (int kt = 0; kt < KT; kt++) {
        // fragments of current tile from LDS (linear 1KB bursts)
        const u16* base = &ldsA[cur][lane * 8];
        bf16x8 ah[4], al[4];
#pragma unroll
        for (int i = 0; i < 4; i++) {
            ah[i] = *(const bf16x8*)(base + i * 512);
            al[i] = *(const bf16x8*)(base + i * 512 + 2048);
        }
        // B fragments direct to VGPR (L2-resident); wave w takes frags w*4+j
        const u16* bH = Bh + ((size_t)kt * 16 + wid * 4) * 512 + lane * 8;
        const u16* bL = Bl + ((size_t)kt * 16 + wid * 4) * 512 + lane * 8;
        bf16x8 bh[4], bl[4];
#pragma unroll
        for (int j = 0; j < 4; j++) {
            bh[j] = *(const bf16x8*)(bH + j * 512);
            bl[j] = *(const bf16x8*)(bL + j * 512);
        }

        // stage next tile into other buffer; prefetch tile kt+2
        if (kt + 1 < KT) {
            float vv[8] = {va0.x, va0.y, va0.z, va0.w, va1.x, va1.y, va1.z, va1.w};
            bf16x8 hv, lv;
#pragma unroll
            for (int e = 0; e < 8; e++) {
                const u16 h = f2bf(vv[e]);
                hv[e] = (short)h;
                lv[e] = (short)f2bf(vv[e] - bf2f(h));
            }
            u16* wr = &ldsA[cur ^ 1][wid * 512 + lane * 8];
            *(bf16x8*)wr = hv;
            *(bf16x8*)(wr + 2048) = lv;
            if (aptr && kt + 2 < KT) {
                va0 = *(const float4*)(aptr + (kt + 2) * 32);
                va1 = *(const float4*)(aptr + (kt + 2) * 32 + 4);
            }
        }

#pragma unroll
        for (int i = 0; i < 4; i++)
#pragma unroll
            for (int j = 0; j < 4; j++) {
                acc[i][j] = __builtin_amdgcn_mfma_f32_16x16x32_bf16(ah[i], bh[j], acc[i][j], 0, 0, 0);
                acc[i][j] = __builtin_amdgcn_mfma_f32_16x16x32_bf16(al[i], bh[j], acc[i][j], 0, 0, 0);
                acc[i][j] = __builtin_amdgcn_mfma_f32_16x16x32_bf16(ah[i], bl[j], acc[i][j], 0, 0, 0);
            }
        __syncthreads();
        cur ^= 1;
    }

    // epilogue: C/D layout col = lane&15, row = (lane>>4)*4 + r
    const int r0 = rowblk * 64;
    const int colb = wid * 64 + (lane & 15);
#pragma unroll
    for (int i = 0; i < 4; i++) {
#pragma unroll
        for (int r = 0; r < 4; r++) {
            const int row = r0 + i * 16 + (lane >> 4) * 4 + r;
            if (row < M) {
#pragma unroll
                for (int j = 0; j < 4; j++)
                    C[(size_t)row * HC + colb + j * 16] = acc[i][j][r];
            }
        }
    }
}

// ---------------------------------------------------------------------------
// Per-node attention coefficients
// ---------------------------------------------------------------------------
__global__ __launch_bounds__(256) void attn_coef(const float* __restrict__ h,
                                                 const float* __restrict__ att_s,
                                                 const float* __restrict__ att_d,
                                                 float* __restrict__ a_src,
                                                 float* __restrict__ a_dst) {
    const int n = blockIdx.x;
    const int tid = threadIdx.x;
    const float hv = h[(size_t)n * HC + tid];
    float p = hv * att_s[tid];
    float q = hv * att_d[tid];
#pragma unroll
    for (int m = 16; m >= 1; m >>= 1) {
        p += __shfl_xor(p, m);
        q += __shfl_xor(q, m);
    }
    if ((tid & 31) == 0) {
        a_src[n * NH + (tid >> 5)] = p;
        a_dst[n * NH + (tid >> 5)] = q;
    }
}

// ---------------------------------------------------------------------------
// CSR build: count, two-level scan, scatter
// ---------------------------------------------------------------------------
__global__ void count_deg(const int* __restrict__ dst, int E, int ET, int* __restrict__ deg) {
    const int e = blockIdx.x * blockDim.x + threadIdx.x;
    if (e >= ET) return;
    const int d = (e < E) ? dst[e] : (e - E);
    atomicAdd(&deg[d], 1);
}

__global__ __launch_bounds__(256) void scan_block(const int* __restrict__ deg,
                                                  int* __restrict__ row_ptr,
                                                  int* __restrict__ partials, int N) {
    __shared__ int sd[256];
    const int tid = threadIdx.x;
    const int base = blockIdx.x * 1024 + tid * 4;
    int v0 = (base + 0 < N) ? deg[base + 0] : 0;
    int v1 = (base + 1 < N) ? deg[base + 1] : 0;
    int v2 = (base + 2 < N) ? deg[base + 2] : 0;
    int v3 = (base + 3 < N) ? deg[base + 3] : 0;
    const int tsum = v0 + v1 + v2 + v3;
    sd[tid] = tsum;
    __syncthreads();
    int run = tsum;
    for (int off = 1; off < 256; off <<= 1) {
        int t = 0;
        if (tid >= off) t = sd[tid - off];
        __syncthreads();
        run += t;
        sd[tid] = run;
        __syncthreads();
    }
    const int excl = run - tsum;
    int s0 = excl + v0, s1 = s0 + v1, s2 = s1 + v2, s3 = s2 + v3;
    if (base + 0 < N) row_ptr[base + 1] = s0;
    if (base + 1 < N) row_ptr[base + 2] = s1;
    if (base + 2 < N) row_ptr[base + 3] = s2;
    if (base + 3 < N) row_ptr[base + 4] = s3;
    if (tid == 255) partials[blockIdx.x] = run;
}

__global__ __launch_bounds__(1024) void scan_partials(int* __restrict__ partials, int nb) {
    __shared__ int sd[1024];
    const int tid = threadIdx.x;
    int v = (tid < nb) ? partials[tid] : 0;
    sd[tid] = v;
    __syncthreads();
    int run = v;
    for (int off = 1; off < 1024; off <<= 1) {
        int t = 0;
        if (tid >= off) t = sd[tid - off];
        __syncthreads();
        run += t;
        sd[tid] = run;
        __syncthreads();
    }
    if (tid < nb) partials[tid] = run - v;  // exclusive
}

__global__ __launch_bounds__(256) void scan_add(int* __restrict__ row_ptr,
                                                const int* __restrict__ partials, int N) {
    const int i = blockIdx.x * 256 + threadIdx.x;
    if (i == 0) row_ptr[0] = 0;
    if (i < N) row_ptr[i + 1] += partials[i >> 10];
}

__global__ void scatter_edges(const int* __restrict__ dst, int E, int ET,
                              const int* __restrict__ row_ptr, int* __restrict__ cursor,
                              int* __restrict__ eids) {
    const int e = blockIdx.x * blockDim.x + threadIdx.x;
    if (e >= ET) return;
    const int d = (e < E) ? dst[e] : (e - E);
    const int pos = atomicAdd(&cursor[d], 1);
    eids[row_ptr[d] + pos] = e;
}

// ---------------------------------------------------------------------------
// GAT aggregation, one WAVE per dst node (wave-synchronous, no block barriers).
// ---------------------------------------------------------------------------
__global__ __launch_bounds__(256) void gat_aggregate_wave(
    const float* __restrict__ h, const float* __restrict__ a_src,
    const float* __restrict__ a_dst, const int* __restrict__ row_ptr,
    const int* __restrict__ eids, const int* __restrict__ src_arr, int E,
    const float* __restrict__ bias, float* __restrict__ out, int N) {
    __shared__ int   s_src[4][CHW];
    __shared__ float s_ev[4][CHW][NH];

    const int tid = threadIdx.x;
    const int wv = tid >> 6;
    const int lane = tid & 63;
    const int n = blockIdx.x * 4 + wv;
    if (n >= N) return;

    const int beg = row_ptr[n];
    const int deg = row_ptr[n + 1] - beg;
    const int jj = lane >> 3;   // edge slot 0..7
    const int hh = lane & 7;    // head for softmax lanes
    const int g4 = lane >> 3;   // head for gather features

    const float adh = a_dst[n * NH + hh];
    float m_run = -1e30f, d_run = 0.f;
    f32x4 acc = (f32x4)0.f;

    for (int c0 = 0; c0 < deg; c0 += CHW) {
        const int chlen = min(CHW, deg - c0);

        float lmax = -1e30f;
        for (int p = 0; p < chlen; p += 8) {
            const int j = p + jj;
            if (j < chlen) {
                const int e = eids[beg + c0 + j];
                const int s = (e < E) ? src_arr[e] : (e - E);
                if (hh == 0) s_src[wv][j] = s;
                float v = a_src[s * NH + hh] + adh;
                v = (v > 0.f) ? v : NEG_SLOPE * v;
                s_ev[wv][j][hh] = v;
                lmax = fmaxf(lmax, v);
            }
        }
        lmax = fmaxf(lmax, __shfl_xor(lmax, 8));
        lmax = fmaxf(lmax, __shfl_xor(lmax, 16));
        lmax = fmaxf(lmax, __shfl_xor(lmax, 32));
        const float mo = m_run;
        const float mn = fmaxf(mo, lmax);
        const float scl = __expf(mo - mn);
        m_run = mn;

        float lsum = 0.f;
        for (int p = 0; p < chlen; p += 8) {
            const int j = p + jj;
            if (j < chlen) {
                const float pv = __expf(s_ev[wv][j][hh] - mn);
                s_ev[wv][j][hh] = pv;
                lsum += pv;
            }
        }
        lsum += __shfl_xor(lsum, 8);
        lsum += __shfl_xor(lsum, 16);
        lsum += __shfl_xor(lsum, 32);
        d_run = d_run * scl + lsum;

        __asm__ volatile("s_waitcnt lgkmcnt(0)" ::: "memory");

        const float scl4 = __shfl(scl, g4);
        f32x4 t = (f32x4)0.f;
        int j = 0;
        for (; j + 2 <= chlen; j += 2) {
            const int s0 = s_src[wv][j];
            const int s1 = s_src[wv][j + 1];
            const float p0 = s_ev[wv][j][g4];
            const float p1 = s_ev[wv][j + 1][g4];
            const f32x4 h0 = *(const f32x4*)&h[(size_t)s0 * HC + lane * 4];
            const f32x4 h1 = *(const f32x4*)&h[(size_t)s1 * HC + lane * 4];
#pragma unroll
            for (int q = 0; q < 4; q++) t[q] += p0 * h0[q] + p1 * h1[q];
        }
        if (j < chlen) {
            const int s0 = s_src[wv][j];
            const float p0 = s_ev[wv][j][g4];
            const f32x4 h0 = *(const f32x4*)&h[(size_t)s0 * HC + lane * 4];
#pragma unroll
            for (int q = 0; q < 4; q++) t[q] += p0 * h0[q];
        }
#pragma unroll
        for (int q = 0; q < 4; q++) acc[q] = acc[q] * scl4 + t[q];
    }

    const float invd = 1.f / (__shfl(d_run, g4) + 1e-16f);
    const f32x4 bv = *(const f32x4*)&bias[lane * 4];
    f32x4 o;
#pragma unroll
    for (int q = 0; q < 4; q++) o[q] = fmaxf(acc[q] * invd + bv[q], 0.f);
    *(f32x4*)&out[(size_t)n * HC + lane * 4] = o;
}

// ---------------------------------------------------------------------------
// Pooling stage 1
// ---------------------------------------------------------------------------
__global__ __launch_bounds__(256) void pool_partial(const float* __restrict__ h,
                                                    const int* __restrict__ batch, int N,
                                                    float* __restrict__ sums) {
    __shared__ int bs[64];
    const int tid = threadIdx.x;
    const int base = blockIdx.x * 64;
    const int cnt = min(64, N - base);
    if (tid < 64 && tid < cnt) bs[tid] = batch[base + tid];
    __syncthreads();

    float acc = 0.f;
    int cur = bs[0];
    for (int i = 0; i < cnt; i++) {
        const int g = bs[i];
        if (g != cur) {
            atomicAdd(&sums[(size_t)cur * HC + tid], acc);
            acc = 0.f;
            cur = g;
        }
        acc += h[(size_t)(base + i) * HC + tid];
    }
    atomicAdd(&sums[(size_t)cur * HC + tid], acc);
}

__global__ __launch_bounds__(256) void pool_div(float* __restrict__ sums,
                                                const int* __restrict__ batch, int N) {
    const int g = blockIdx.x;
    const int tid = threadIdx.x;
    int lo = 0, hi = N;
    while (lo < hi) {
        const int mid = (lo + hi) >> 1;
        if (batch[mid] < g) lo = mid + 1; else hi = mid;
    }
    const int start = lo;
    hi = N;
    while (lo < hi) {
        const int mid = (lo + hi) >> 1;
        if (batch[mid] < g + 1) lo = mid + 1; else hi = mid;
    }
    const float inv = 1.f / fmaxf((float)(lo - start), 1.0f);
    sums[(size_t)g * HC + tid] *= inv;
}

// ---------------------------------------------------------------------------
// MLP head
// ---------------------------------------------------------------------------
__global__ __launch_bounds__(128) void mlp_head(const float* __restrict__ pooled,
                                                const float* __restrict__ w1,
                                                const float* __restrict__ b1,
                                                const float* __restrict__ w2,
                                                const float* __restrict__ b2,
                                                float* __restrict__ out) {
    const int g = blockIdx.x;
    const int tid = threadIdx.x;
    __shared__ float p[HC];
    p[tid] = pooled[g * HC + tid];
    p[tid + 128] = pooled[g * HC + tid + 128];
    __syncthreads();
    float z = b1[tid];
#pragma unroll 8
    for (int k = 0; k < HC; k++) z += p[k] * w1[k * 128 + tid];
    z = fmaxf(z, 0.f);
    float t = z * w2[tid];
#pragma unroll
    for (int m = 32; m >= 1; m >>= 1) t += __shfl_xor(t, m);
    __shared__ float ws2[2];
    if ((tid & 63) == 0) ws2[tid >> 6] = t;
    __syncthreads();
    if (tid == 0) out[g] = ws2[0] + ws2[1] + b2[0];
}

// ---------------------------------------------------------------------------
// Host-side launcher
// ---------------------------------------------------------------------------
extern "C" void kernel_launch(void* const* d_in, const int* in_sizes, int n_in,
                              void* d_out, int out_size, void* d_ws, size_t ws_size,
                              hipStream_t stream) {
    const float* x      = (const float*)d_in[0];
    const int*   ei     = (const int*)d_in[1];
    const int*   batch  = (const int*)d_in[2];
    const float* W1     = (const float*)d_in[3];
    const float* as1    = (const float*)d_in[4];
    const float* ad1    = (const float*)d_in[5];
    const float* b1     = (const float*)d_in[6];
    const float* W2     = (const float*)d_in[7];
    const float* as2    = (const float*)d_in[8];
    const float* ad2    = (const float*)d_in[9];
    const float* b2     = (const float*)d_in[10];
    const float* lin1w  = (const float*)d_in[11];
    const float* lin1b  = (const float*)d_in[12];
    const float* lin2w  = (const float*)d_in[13];
    const float* lin2b  = (const float*)d_in[14];

    const int N   = in_sizes[2];       // 50000
    const int E   = in_sizes[1] / 2;   // 800000
    const int ET  = E + N;
    const int Fin = in_sizes[0] / N;   // 1280
    const int NG  = 64;

    const int nRB = (N + 63) / 64;
    const int nScanBlk = (N + 1023) / 1024;

    const int* src_arr = ei;
    const int* dst_arr = ei + E;

    char* ws = (char*)d_ws;
    size_t off = 0;
    auto alloc = [&](size_t bytes) {
        void* p = ws + off;
        off += (bytes + 255) & ~(size_t)255;
        return p;
    };
    float* h_gemm  = (float*)alloc((size_t)N * HC * sizeof(float));
    float* h_agg   = (float*)alloc((size_t)N * HC * sizeof(float));
    float* a_src   = (float*)alloc((size_t)N * NH * sizeof(float));
    float* a_dst   = (float*)alloc((size_t)N * NH * sizeof(float));
    int*   deg     = (int*)alloc((size_t)N * sizeof(int));
    int*   cursor  = (int*)alloc((size_t)N * sizeof(int));
    int*   row_ptr = (int*)alloc((size_t)(N + 1) * sizeof(int));
    int*   partials= (int*)alloc((size_t)1024 * sizeof(int));
    int*   eids    = (int*)alloc((size_t)ET * sizeof(int));
    float* pooled  = (float*)alloc((size_t)NG * HC * sizeof(float));
    u16* Bh = (u16*)alloc((size_t)Fin * HC * sizeof(u16));
    u16* Bl = (u16*)alloc((size_t)Fin * HC * sizeof(u16));
    (void)ws_size; (void)n_in; (void)out_size;

    // ---- CSR build ----
    hipMemsetAsync(deg, 0, (size_t)N * sizeof(int), stream);
    hipMemsetAsync(cursor, 0, (size_t)N * sizeof(int), stream);
    {
        const int blocks = (ET + 255) / 256;
        count_deg<<<blocks, 256, 0, stream>>>(dst_arr, E, ET, deg);
        scan_block<<<nScanBlk, 256, 0, stream>>>(deg, row_ptr, partials, N);
        scan_partials<<<1, 1024, 0, stream>>>(partials, nScanBlk);
        scan_add<<<(N + 255) / 256, 256, 0, stream>>>(row_ptr, partials, N);
        scatter_edges<<<blocks, 256, 0, stream>>>(dst_arr, E, ET, row_ptr, cursor, eids);
    }

    const int aggBlocks = (N + 3) / 4;

    // ---- Layer 1 ----
    pack_b_split<<<(Fin / 32) * 4, 256, 0, stream>>>(W1, Fin, Bh, Bl);
    gemm_fused_split<<<nRB, 256, 0, stream>>>(x, Bh, Bl, h_gemm, N, Fin);
    attn_coef<<<N, 256, 0, stream>>>(h_gemm, as1, ad1, a_src, a_dst);
    gat_aggregate_wave<<<aggBlocks, 256, 0, stream>>>(h_gemm, a_src, a_dst, row_ptr,
                                                      eids, src_arr, E, b1, h_agg, N);

    // ---- Layer 2 ----
    pack_b_split<<<(HC / 32) * 4, 256, 0, stream>>>(W2, HC, Bh, Bl);
    gemm_fused_split<<<nRB, 256, 0, stream>>>(h_agg, Bh, Bl, h_gemm, N, HC);
    attn_coef<<<N, 256, 0, stream>>>(h_gemm, as2, ad2, a_src, a_dst);
    gat_aggregate_wave<<<aggBlocks, 256, 0, stream>>>(h_gemm, a_src, a_dst, row_ptr,
                                                      eids, src_arr, E, b2, h_agg, N);

    // ---- Pool + MLP head ----
    hipMemsetAsync(pooled, 0, (size_t)NG * HC * sizeof(float), stream);
    pool_partial<<<(N + 63) / 64, 256, 0, stream>>>(h_agg, batch, N, pooled);
    pool_div<<<NG, 256, 0, stream>>>(pooled, batch, N);
    mlp_head<<<NG, 128, 0, stream>>>(pooled, lin1w, lin1b, lin2w, lin2b, (float*)d_out);
}

// Round 7
// 609.464 us; speedup vs baseline: 2.7845x; 1.0527x over previous
//
#include <hip/hip_runtime.h>
#include <hip/hip_bf16.h>
#include <math.h>

#define HC 256
#define NH 8
#define NEG_SLOPE 0.2f
#define CHW 64   // edges per chunk per wave (aggregation)

typedef unsigned short u16;
typedef __attribute__((ext_vector_type(8))) short bf16x8;
typedef __attribute__((ext_vector_type(4))) short bf16x4;
typedef __attribute__((ext_vector_type(4))) float f32x4;

__device__ __forceinline__ u16 f2bf(float f) {
    unsigned int u = __float_as_uint(f);
    u += 0x7FFFu + ((u >> 16) & 1u);
    return (u16)(u >> 16);
}
__device__ __forceinline__ float bf2f(u16 s) {
    return __uint_as_float(((unsigned int)s) << 16);
}

// ---------------------------------------------------------------------------
// pack B (fp32 [K x 256]) -> hi/lo, fragment-major:
// chunk g = kt*1024 + f*64 + lane; col = f*16 + (lane&15); k = kt*32+(lane>>4)*8+e
// ---------------------------------------------------------------------------
__global__ __launch_bounds__(256) void pack_b_split(const float* __restrict__ B, int K,
                                                    u16* __restrict__ Bh,
                                                    u16* __restrict__ Bl) {
    const int g = blockIdx.x * 256 + threadIdx.x;
    const int lane = g & 63;
    const int f = (g >> 6) & 15;
    const int kt = g >> 10;
    const int col = f * 16 + (lane & 15);
    const int k0 = kt * 32 + (lane >> 4) * 8;
    bf16x8 hv, lv;
#pragma unroll
    for (int e = 0; e < 8; e++) {
        const float v = B[(size_t)(k0 + e) * HC + col];
        const u16 h = f2bf(v);
        hv[e] = (short)h;
        lv[e] = (short)f2bf(v - bf2f(h));
    }
    const size_t off = (size_t)g * 8;
    *(bf16x8*)(Bh + off) = hv;
    *(bf16x8*)(Bl + off) = lv;
}

// ---------------------------------------------------------------------------
// Fused split-precision MFMA GEMM, 512 threads / 8 waves per block.
// Tile M=64, N=256. Wave w owns cols [w*32, w*32+32): col-frags w*2, w*2+1.
// Staging: thread t owns 4 fp32 of A (row-frag t>>7, frag-lane (t>>1)&63,
//   k-half t&1), converts to hi/lo bf16, ds_write_b64 fragment-major (linear).
// Double-buffered LDS (2 x 8KB), one barrier per k-tile, A prefetched in regs.
// C = Ah*Bh + Al*Bh + Ah*Bl  (~fp32 accuracy).
// ---------------------------------------------------------------------------
__global__ __launch_bounds__(512) void gemm_fused_split(
    const float* __restrict__ A,
    const u16* __restrict__ Bh, const u16* __restrict__ Bl,
    float* __restrict__ C, int M, int K) {
    __shared__ u16 ldsA[2][4096];   // [buf][hi:0..2048 | lo:2048..4096]
    const int tid = threadIdx.x;
    const int wid = tid >> 6;        // 0..7
    const int lane = tid & 63;
    const int rowblk = blockIdx.x;
    const int KT = K >> 5;

    f32x4 acc[4][2];
#pragma unroll
    for (int i = 0; i < 4; i++)
#pragma unroll
        for (int j = 0; j < 2; j++) acc[i][j] = (f32x4)0.f;

    // staging map: 512 threads cover 64x32 fp32 tile, 4 elems each
    const int f2 = tid >> 7;             // row-frag 0..3
    const int sl = (tid >> 1) & 63;      // frag lane
    const int h2 = tid & 1;              // k-half (0: elems 0-3, 1: elems 4-7)
    const int srow = f2 * 16 + (sl & 15);
    const int skq = (sl >> 4) * 8 + h2 * 4;
    const int grow = rowblk * 64 + srow;
    const float* aptr = (grow < M) ? (A + (size_t)grow * K + skq) : nullptr;
    const int wslot = f2 * 512 + sl * 8 + h2 * 4;   // u16 offset in half-buffer

    auto cvt_store = [&](int buf, float4 v) {
        bf16x4 hv, lv;
        const float vv[4] = {v.x, v.y, v.z, v.w};
#pragma unroll
        for (int e = 0; e < 4; e++) {
            const u16 h = f2bf(vv[e]);
            hv[e] = (short)h;
            lv[e] = (short)f2bf(vv[e] - bf2f(h));
        }
        *(bf16x4*)&ldsA[buf][wslot] = hv;
        *(bf16x4*)&ldsA[buf][wslot + 2048] = lv;
    };

    float4 pf = make_float4(0.f, 0.f, 0.f, 0.f);
    if (aptr) pf = *(const float4*)aptr;
    cvt_store(0, pf);                       // tile 0 -> buf 0
    pf = make_float4(0.f, 0.f, 0.f, 0.f);
    if (aptr && KT > 1) pf = *(const float4*)(aptr + 32);   // tile 1 in regs
    __syncthreads();

    int cur = 0;
    for (int kt = 0; kt < KT; kt++) {
        // B fragments for this wave (L2-resident): frags kt*16 + wid*2 + j
        const u16* bHp = Bh + ((size_t)kt * 16 + wid * 2) * 512 + lane * 8;
        const u16* bLp = Bl + ((size_t)kt * 16 + wid * 2) * 512 + lane * 8;
        bf16x8 bh[2], bl[2];
#pragma unroll
        for (int j = 0; j < 2; j++) {
            bh[j] = *(const bf16x8*)(bHp + j * 512);
            bl[j] = *(const bf16x8*)(bLp + j * 512);
        }
        // A fragments of current tile (linear 1KB bursts per wave)
        const u16* base = &ldsA[cur][lane * 8];
        bf16x8 ah[4], al[4];
#pragma unroll
        for (int i = 0; i < 4; i++) {
            ah[i] = *(const bf16x8*)(base + i * 512);
            al[i] = *(const bf16x8*)(base + i * 512 + 2048);
        }
        // stage next tile into other buffer; prefetch tile kt+2
        if (kt + 1 < KT) {
            cvt_store(cur ^ 1, pf);
            pf = make_float4(0.f, 0.f, 0.f, 0.f);
            if (aptr && kt + 2 < KT) pf = *(const float4*)(aptr + (kt + 2) * 32);
        }
#pragma unroll
        for (int i = 0; i < 4; i++)
#pragma unroll
            for (int j = 0; j < 2; j++) {
                acc[i][j] = __builtin_amdgcn_mfma_f32_16x16x32_bf16(ah[i], bh[j], acc[i][j], 0, 0, 0);
                acc[i][j] = __builtin_amdgcn_mfma_f32_16x16x32_bf16(al[i], bh[j], acc[i][j], 0, 0, 0);
                acc[i][j] = __builtin_amdgcn_mfma_f32_16x16x32_bf16(ah[i], bl[j], acc[i][j], 0, 0, 0);
            }
        __syncthreads();
        cur ^= 1;
    }

    // epilogue: C/D layout col = lane&15, row = (lane>>4)*4 + r
    const int r0 = rowblk * 64;
    const int colb = wid * 32 + (lane & 15);
#pragma unroll
    for (int i = 0; i < 4; i++) {
#pragma unroll
        for (int r = 0; r < 4; r++) {
            const int row = r0 + i * 16 + (lane >> 4) * 4 + r;
            if (row < M) {
#pragma unroll
                for (int j = 0; j < 2; j++)
                    C[(size_t)row * HC + colb + j * 16] = acc[i][j][r];
            }
        }
    }
}

// ---------------------------------------------------------------------------
// Per-node attention coefficients
// ---------------------------------------------------------------------------
__global__ __launch_bounds__(256) void attn_coef(const float* __restrict__ h,
                                                 const float* __restrict__ att_s,
                                                 const float* __restrict__ att_d,
                                                 float* __restrict__ a_src,
                                                 float* __restrict__ a_dst) {
    const int n = blockIdx.x;
    const int tid = threadIdx.x;
    const float hv = h[(size_t)n * HC + tid];
    float p = hv * att_s[tid];
    float q = hv * att_d[tid];
#pragma unroll
    for (int m = 16; m >= 1; m >>= 1) {
        p += __shfl_xor(p, m);
        q += __shfl_xor(q, m);
    }
    if ((tid & 31) == 0) {
        a_src[n * NH + (tid >> 5)] = p;
        a_dst[n * NH + (tid >> 5)] = q;
    }
}

// ---------------------------------------------------------------------------
// CSR build: count, two-level scan, scatter (stores resolved src ids)
// ---------------------------------------------------------------------------
__global__ void count_deg(const int* __restrict__ dst, int E, int ET, int* __restrict__ deg) {
    const int e = blockIdx.x * blockDim.x + threadIdx.x;
    if (e >= ET) return;
    const int d = (e < E) ? dst[e] : (e - E);
    atomicAdd(&deg[d], 1);
}

__global__ __launch_bounds__(256) void scan_block(const int* __restrict__ deg,
                                                  int* __restrict__ row_ptr,
                                                  int* __restrict__ partials, int N) {
    __shared__ int sd[256];
    const int tid = threadIdx.x;
    const int base = blockIdx.x * 1024 + tid * 4;
    int v0 = (base + 0 < N) ? deg[base + 0] : 0;
    int v1 = (base + 1 < N) ? deg[base + 1] : 0;
    int v2 = (base + 2 < N) ? deg[base + 2] : 0;
    int v3 = (base + 3 < N) ? deg[base + 3] : 0;
    const int tsum = v0 + v1 + v2 + v3;
    sd[tid] = tsum;
    __syncthreads();
    int run = tsum;
    for (int off = 1; off < 256; off <<= 1) {
        int t = 0;
        if (tid >= off) t = sd[tid - off];
        __syncthreads();
        run += t;
        sd[tid] = run;
        __syncthreads();
    }
    const int excl = run - tsum;
    int s0 = excl + v0, s1 = s0 + v1, s2 = s1 + v2, s3 = s2 + v3;
    if (base + 0 < N) row_ptr[base + 1] = s0;
    if (base + 1 < N) row_ptr[base + 2] = s1;
    if (base + 2 < N) row_ptr[base + 3] = s2;
    if (base + 3 < N) row_ptr[base + 4] = s3;
    if (tid == 255) partials[blockIdx.x] = run;
}

__global__ __launch_bounds__(1024) void scan_partials(int* __restrict__ partials, int nb) {
    __shared__ int sd[1024];
    const int tid = threadIdx.x;
    int v = (tid < nb) ? partials[tid] : 0;
    sd[tid] = v;
    __syncthreads();
    int run = v;
    for (int off = 1; off < 1024; off <<= 1) {
        int t = 0;
        if (tid >= off) t = sd[tid - off];
        __syncthreads();
        run += t;
        sd[tid] = run;
        __syncthreads();
    }
    if (tid < nb) partials[tid] = run - v;  // exclusive
}

__global__ __launch_bounds__(256) void scan_add(int* __restrict__ row_ptr,
                                                const int* __restrict__ partials, int N) {
    const int i = blockIdx.x * 256 + threadIdx.x;
    if (i == 0) row_ptr[0] = 0;
    if (i < N) row_ptr[i + 1] += partials[i >> 10];
}

__global__ void scatter_edges(const int* __restrict__ src_in, const int* __restrict__ dst,
                              int E, int ET, const int* __restrict__ row_ptr,
                              int* __restrict__ cursor, int* __restrict__ esrc) {
    const int e = blockIdx.x * blockDim.x + threadIdx.x;
    if (e >= ET) return;
    const int d = (e < E) ? dst[e] : (e - E);
    const int s = (e < E) ? src_in[e] : (e - E);
    const int pos = atomicAdd(&cursor[d], 1);
    esrc[row_ptr[d] + pos] = s;
}

// ---------------------------------------------------------------------------
// GAT aggregation, one WAVE per dst node (wave-synchronous, no block barriers).
// esrc holds pre-resolved source node ids per CSR slot.
// ---------------------------------------------------------------------------
__global__ __launch_bounds__(256) void gat_aggregate_wave(
    const float* __restrict__ h, const float* __restrict__ a_src,
    const float* __restrict__ a_dst, const int* __restrict__ row_ptr,
    const int* __restrict__ esrc, const float* __restrict__ bias,
    float* __restrict__ out, int N) {
    __shared__ int   s_src[4][CHW];
    __shared__ float s_ev[4][CHW][NH];

    const int tid = threadIdx.x;
    const int wv = tid >> 6;
    const int lane = tid & 63;
    const int n = blockIdx.x * 4 + wv;
    if (n >= N) return;

    const int beg = row_ptr[n];
    const int deg = row_ptr[n + 1] - beg;
    const int jj = lane >> 3;   // edge slot 0..7
    const int hh = lane & 7;    // head for softmax lanes
    const int g4 = lane >> 3;   // head for gather features

    const float adh = a_dst[n * NH + hh];
    float m_run = -1e30f, d_run = 0.f;
    f32x4 acc = (f32x4)0.f;

    for (int c0 = 0; c0 < deg; c0 += CHW) {
        const int chlen = min(CHW, deg - c0);

        float lmax = -1e30f;
        for (int p = 0; p < chlen; p += 8) {
            const int j = p + jj;
            if (j < chlen) {
                const int s = esrc[beg + c0 + j];
                if (hh == 0) s_src[wv][j] = s;
                float v = a_src[s * NH + hh] + adh;
                v = (v > 0.f) ? v : NEG_SLOPE * v;
                s_ev[wv][j][hh] = v;
                lmax = fmaxf(lmax, v);
            }
        }
        lmax = fmaxf(lmax, __shfl_xor(lmax, 8));
        lmax = fmaxf(lmax, __shfl_xor(lmax, 16));
        lmax = fmaxf(lmax, __shfl_xor(lmax, 32));
        const float mo = m_run;
        const float mn = fmaxf(mo, lmax);
        const float scl = __expf(mo - mn);
        m_run = mn;

        float lsum = 0.f;
        for (int p = 0; p < chlen; p += 8) {
            const int j = p + jj;
            if (j < chlen) {
                const float pv = __expf(s_ev[wv][j][hh] - mn);
                s_ev[wv][j][hh] = pv;
                lsum += pv;
            }
        }
        lsum += __shfl_xor(lsum, 8);
        lsum += __shfl_xor(lsum, 16);
        lsum += __shfl_xor(lsum, 32);
        d_run = d_run * scl + lsum;

        __asm__ volatile("s_waitcnt lgkmcnt(0)" ::: "memory");

        const float scl4 = __shfl(scl, g4);
        f32x4 t = (f32x4)0.f;
        int j = 0;
        for (; j + 2 <= chlen; j += 2) {
            const int s0 = s_src[wv][j];
            const int s1 = s_src[wv][j + 1];
            const float p0 = s_ev[wv][j][g4];
            const float p1 = s_ev[wv][j + 1][g4];
            const f32x4 h0 = *(const f32x4*)&h[(size_t)s0 * HC + lane * 4];
            const f32x4 h1 = *(const f32x4*)&h[(size_t)s1 * HC + lane * 4];
#pragma unroll
            for (int q = 0; q < 4; q++) t[q] += p0 * h0[q] + p1 * h1[q];
        }
        if (j < chlen) {
            const int s0 = s_src[wv][j];
            const float p0 = s_ev[wv][j][g4];
            const f32x4 h0 = *(const f32x4*)&h[(size_t)s0 * HC + lane * 4];
#pragma unroll
            for (int q = 0; q < 4; q++) t[q] += p0 * h0[q];
        }
#pragma unroll
        for (int q = 0; q < 4; q++) acc[q] = acc[q] * scl4 + t[q];
    }

    const float invd = 1.f / (__shfl(d_run, g4) + 1e-16f);
    const f32x4 bv = *(const f32x4*)&bias[lane * 4];
    f32x4 o;
#pragma unroll
    for (int q = 0; q < 4; q++) o[q] = fmaxf(acc[q] * invd + bv[q], 0.f);
    *(f32x4*)&out[(size_t)n * HC + lane * 4] = o;
}

// ---------------------------------------------------------------------------
// Pooling stage 1
// ---------------------------------------------------------------------------
__global__ __launch_bounds__(256) void pool_partial(const float* __restrict__ h,
                                                    const int* __restrict__ batch, int N,
                                                    float* __restrict__ sums) {
    __shared__ int bs[64];
    const int tid = threadIdx.x;
    const int base = blockIdx.x * 64;
    const int cnt = min(64, N - base);
    if (tid < 64 && tid < cnt) bs[tid] = batch[base + tid];
    __syncthreads();

    float acc = 0.f;
    int cur = bs[0];
    for (int i = 0; i < cnt; i++) {
        const int g = bs[i];
        if (g != cur) {
            atomicAdd(&sums[(size_t)cur * HC + tid], acc);
            acc = 0.f;
            cur = g;
        }
        acc += h[(size_t)(base + i) * HC + tid];
    }
    atomicAdd(&sums[(size_t)cur * HC + tid], acc);
}

__global__ __launch_bounds__(256) void pool_div(float* __restrict__ sums,
                                                const int* __restrict__ batch, int N) {
    const int g = blockIdx.x;
    const int tid = threadIdx.x;
    int lo = 0, hi = N;
    while (lo < hi) {
        const int mid = (lo + hi) >> 1;
        if (batch[mid] < g) lo = mid + 1; else hi = mid;
    }
    const int start = lo;
    hi = N;
    while (lo < hi) {
        const int mid = (lo + hi) >> 1;
        if (batch[mid] < g + 1) lo = mid + 1; else hi = mid;
    }
    const float inv = 1.f / fmaxf((float)(lo - start), 1.0f);
    sums[(size_t)g * HC + tid] *= inv;
}

// ---------------------------------------------------------------------------
// MLP head
// ---------------------------------------------------------------------------
__global__ __launch_bounds__(128) void mlp_head(const float* __restrict__ pooled,
                                                const float* __restrict__ w1,
                                                const float* __restrict__ b1,
                                                const float* __restrict__ w2,
                                                const float* __restrict__ b2,
                                                float* __restrict__ out) {
    const int g = blockIdx.x;
    const int tid = threadIdx.x;
    __shared__ float p[HC];
    p[tid] = pooled[g * HC + tid];
    p[tid + 128] = pooled[g * HC + tid + 128];
    __syncthreads();
    float z = b1[tid];
#pragma unroll 8
    for (int k = 0; k < HC; k++) z += p[k] * w1[k * 128 + tid];
    z = fmaxf(z, 0.f);
    float t = z * w2[tid];
#pragma unroll
    for (int m = 32; m >= 1; m >>= 1) t += __shfl_xor(t, m);
    __shared__ float ws2[2];
    if ((tid & 63) == 0) ws2[tid >> 6] = t;
    __syncthreads();
    if (tid == 0) out[g] = ws2[0] + ws2[1] + b2[0];
}

// ---------------------------------------------------------------------------
// Host-side launcher
// ---------------------------------------------------------------------------
extern "C" void kernel_launch(void* const* d_in, const int* in_sizes, int n_in,
                              void* d_out, int out_size, void* d_ws, size_t ws_size,
                              hipStream_t stream) {
    const float* x      = (const float*)d_in[0];
    const int*   ei     = (const int*)d_in[1];
    const int*   batch  = (const int*)d_in[2];
    const float* W1     = (const float*)d_in[3];
    const float* as1    = (const float*)d_in[4];
    const float* ad1    = (const float*)d_in[5];
    const float* b1     = (const float*)d_in[6];
    const float* W2     = (const float*)d_in[7];
    const float* as2    = (const float*)d_in[8];
    const float* ad2    = (const float*)d_in[9];
    const float* b2     = (const float*)d_in[10];
    const float* lin1w  = (const float*)d_in[11];
    const float* lin1b  = (const float*)d_in[12];
    const float* lin2w  = (const float*)d_in[13];
    const float* lin2b  = (const float*)d_in[14];

    const int N   = in_sizes[2];       // 50000
    const int E   = in_sizes[1] / 2;   // 800000
    const int ET  = E + N;
    const int Fin = in_sizes[0] / N;   // 1280
    const int NG  = 64;

    const int nRB = (N + 63) / 64;
    const int nScanBlk = (N + 1023) / 1024;

    const int* src_arr = ei;
    const int* dst_arr = ei + E;

    char* ws = (char*)d_ws;
    size_t off = 0;
    auto alloc = [&](size_t bytes) {
        void* p = ws + off;
        off += (bytes + 255) & ~(size_t)255;
        return p;
    };
    float* h_gemm  = (float*)alloc((size_t)N * HC * sizeof(float));
    float* h_agg   = (float*)alloc((size_t)N * HC * sizeof(float));
    float* a_src   = (float*)alloc((size_t)N * NH * sizeof(float));
    float* a_dst   = (float*)alloc((size_t)N * NH * sizeof(float));
    int*   deg     = (int*)alloc((size_t)N * sizeof(int));
    int*   cursor  = (int*)alloc((size_t)N * sizeof(int));
    int*   row_ptr = (int*)alloc((size_t)(N + 1) * sizeof(int));
    int*   partials= (int*)alloc((size_t)1024 * sizeof(int));
    int*   esrc    = (int*)alloc((size_t)ET * sizeof(int));
    float* pooled  = (float*)alloc((size_t)NG * HC * sizeof(float));
    u16* Bh = (u16*)alloc((size_t)Fin * HC * sizeof(u16));
    u16* Bl = (u16*)alloc((size_t)Fin * HC * sizeof(u16));
    (void)ws_size; (void)n_in; (void)out_size;

    // ---- CSR build ----
    hipMemsetAsync(deg, 0, (size_t)N * sizeof(int), stream);
    hipMemsetAsync(cursor, 0, (size_t)N * sizeof(int), stream);
    {
        const int blocks = (ET + 255) / 256;
        count_deg<<<blocks, 256, 0, stream>>>(dst_arr, E, ET, deg);
        scan_block<<<nScanBlk, 256, 0, stream>>>(deg, row_ptr, partials, N);
        scan_partials<<<1, 1024, 0, stream>>>(partials, nScanBlk);
        scan_add<<<(N + 255) / 256, 256, 0, stream>>>(row_ptr, partials, N);
        scatter_edges<<<blocks, 256, 0, stream>>>(src_arr, dst_arr, E, ET, row_ptr,
                                                  cursor, esrc);
    }

    const int aggBlocks = (N + 3) / 4;

    // ---- Layer 1 ----
    pack_b_split<<<(Fin / 32) * 4, 256, 0, stream>>>(W1, Fin, Bh, Bl);
    gemm_fused_split<<<nRB, 512, 0, stream>>>(x, Bh, Bl, h_gemm, N, Fin);
    attn_coef<<<N, 256, 0, stream>>>(h_gemm, as1, ad1, a_src, a_dst);
    gat_aggregate_wave<<<aggBlocks, 256, 0, stream>>>(h_gemm, a_src, a_dst, row_ptr,
                                                      esrc, b1, h_agg, N);

    // ---- Layer 2 ----
    pack_b_split<<<(HC / 32) * 4, 256, 0, stream>>>(W2, HC, Bh, Bl);
    gemm_fused_split<<<nRB, 512, 0, stream>>>(h_agg, Bh, Bl, h_gemm, N, HC);
    attn_coef<<<N, 256, 0, stream>>>(h_gemm, as2, ad2, a_src, a_dst);
    gat_aggregate_wave<<<aggBlocks, 256, 0, stream>>>(h_gemm, a_src, a_dst, row_ptr,
                                                      esrc, b2, h_agg, N);

    // ---- Pool + MLP head ----
    hipMemsetAsync(pooled, 0, (size_t)NG * HC * sizeof(float), stream);
    pool_partial<<<(N + 63) / 64, 256, 0, stream>>>(h_agg, batch, N, pooled);
    pool_div<<<NG, 256, 0, stream>>>(pooled, batch, N);
    mlp_head<<<NG, 128, 0, stream>>>(pooled, lin1w, lin1b, lin2w, lin2b, (float*)d_out);
}